// Round 11
// baseline (79.789 us; speedup 1.0000x reference)
//
#include <hip/hip_runtime.h>
#include <stdint.h>

typedef __attribute__((ext_vector_type(8))) short bfrag_t;   // 8 bf16
typedef __attribute__((ext_vector_type(4))) float floatx4;   // MFMA acc

// ---------------- ws layout (bytes) ----------------
#define WFRAG_OFF   0            // bf16 [16kt][18nt][64lane][8j] = 294912
#define GB_OFF      294912       // f32 [32][128]
#define BU_OFF      311296       // f32 [128]
#define BS_OFF      311808       // f32 [32]
#define MEMFRAG_OFF 311936       // bf16 frag [8nt][64][8] = 8192
#define ACC_OFF     327680       // 512 x (accw[4096] | accg[4096]) f32 = 16 MiB
#define NBLK        512

// ---------------- main LDS layout (bytes), NO overlay, 64 KiB exactly ----------------
#define M_A     0        // bf16 swizzled A-tile [32r][512k] = 32768
#define M_XPF   32768    // bf16 B-frag [8nt][64][8] (k=rows) = 8192
#define M_U     40960    // f32 [32][128] = 16384
#define M_SC    57344    // f32 [32][32] = 4096
#define M_PR    61440    // bf16 A-frag [2mt][64][8] (probs, k=s) = 2048
#define M_PRT   63488    // bf16 A-frag [2mt][64][8] (probsT, k=r) = 2048
#define M_LDS   65536

__device__ __forceinline__ unsigned short f2bf(float f) {
    unsigned u = __float_as_uint(f);
    u += 0x7fffu + ((u >> 16) & 1u);
    return (unsigned short)(u >> 16);
}
__device__ __forceinline__ float sigm(float v) {
    return __builtin_amdgcn_rcpf(1.0f + __expf(-v));
}
__device__ __forceinline__ void writefrag(unsigned short* wf, int k, int n, float v) {
    int kt = k >> 5, kk = k & 31;
    int lane = (n & 15) | ((kk >> 3) << 4);
    wf[(((kt * 18) + (n >> 4)) * 64 + lane) * 8 + (kk & 7)] = f2bf(v);
}

// ---------------- prep: frag weights, gate base, biases, mem frags ----------------
__global__ __launch_bounds__(256) void prep_kernel(
    const float* __restrict__ memv, const float* __restrict__ w_in,
    const float* __restrict__ b_in, const float* __restrict__ w_gate,
    const float* __restrict__ b_gate, unsigned char* __restrict__ ws)
{
    int bid = blockIdx.x, t = threadIdx.x;
    unsigned short* wfrag = (unsigned short*)(ws + WFRAG_OFF);
    const float* wg2 = w_gate + 128 * 128;

    if (bid < 256) {
        __shared__ float wrow[2][128];
        int k0 = bid * 2;
        wrow[t >> 7][t & 127] = w_in[(size_t)(k0 + (t >> 7)) * 128 + (t & 127)];
        __syncthreads();
        for (int kl = 0; kl < 2; ++kl) {
            int k = k0 + kl;
            float v;
            if (t < 128) {
                v = wrow[kl][t];
            } else {
                int d = t - 128;
                float acc = 0.f;
                #pragma unroll 16
                for (int j = 0; j < 128; ++j) acc += wrow[kl][j] * wg2[j * 128 + d];
                v = acc;
            }
            writefrag(wfrag, k, t, v);
            if (t < 32) {
                float acc = 0.f;
                #pragma unroll 16
                for (int d = 0; d < 128; ++d) acc += wrow[kl][d] * memv[t * 128 + d];
                writefrag(wfrag, k, 256 + t, acc);
            }
        }
    } else if (bid < 272) {
        int idx = (bid - 256) * 256 + t;
        int s = idx >> 7, d = idx & 127;
        float acc = b_gate[d];
        #pragma unroll 16
        for (int k = 0; k < 128; ++k) acc += memv[s * 128 + k] * w_gate[k * 128 + d];
        ((float*)(ws + GB_OFF))[idx] = acc;
    } else {
        if (t < 128) {
            float acc = 0.f;
            #pragma unroll 16
            for (int j = 0; j < 128; ++j) acc += b_in[j] * wg2[j * 128 + t];
            ((float*)(ws + BU_OFF))[t] = acc;
        }
        if (t < 32) {
            float acc = 0.f;
            #pragma unroll 16
            for (int d = 0; d < 128; ++d) acc += b_in[d] * memv[t * 128 + d];
            ((float*)(ws + BS_OFF))[t] = acc;
        }
        unsigned short* mfr = (unsigned short*)(ws + MEMFRAG_OFF);
        for (int idx = t; idx < 4096; idx += 256) {
            int s = idx >> 7, d = idx & 127;
            mfr[((d >> 4) * 64 + ((d & 15) | (((s >> 3) & 3) << 4))) * 8 + (s & 7)]
                = f2bf(memv[idx]);
        }
    }
}

// ---------------- main: 512 blocks x 512 threads, 32 rows/block, 3 barriers ----------------
__global__ __launch_bounds__(512, 4) void main_kernel(
    const float* __restrict__ x,
    const float* __restrict__ ln_g, const float* __restrict__ ln_b,
    const float* __restrict__ b_in, unsigned char* __restrict__ ws,
    float* __restrict__ out)
{
    __shared__ char smem[M_LDS] __attribute__((aligned(16)));

    int tid = threadIdx.x;
    int w = tid >> 6, l = tid & 63;          // 8 waves
    int lane_lo = l & 15, lane_hi = l >> 4;
    int row_base = blockIdx.x * 32;

    int nf = (w < 2) ? 3 : 2;
    int nts[3] = {w, w + 8, 16 + w};
    const bfrag_t* wf = (const bfrag_t*)(ws + WFRAG_OFF);

    // ===== Phase 1: LayerNorm -> swizzled bf16 A tile [32][512], 4 rows/wave =====
    const float4* x4 = (const float4*)x;
    float4 g0 = ((const float4*)ln_g)[l];
    float4 g1 = ((const float4*)ln_g)[l + 64];
    float4 q0 = ((const float4*)ln_b)[l];
    float4 q1 = ((const float4*)ln_b)[l + 64];

    float4 xa[4], xb[4];
    #pragma unroll
    for (int i = 0; i < 4; ++i) {
        int r = w * 4 + i;
        xa[i] = x4[(size_t)(row_base + r) * 128 + l];
        xb[i] = x4[(size_t)(row_base + r) * 128 + 64 + l];
    }

    bfrag_t bcur[3], bnxt[3], bfar[3];
    #pragma unroll
    for (int i = 0; i < 3; ++i) {
        if (i < nf) {
            bcur[i] = wf[(0 * 18 + nts[i]) * 64 + l];
            bnxt[i] = wf[(1 * 18 + nts[i]) * 64 + l];
        }
    }
    float bin_v = b_in[w * 16 + lane_lo];
    float bu_v  = ((const float*)(ws + BU_OFF))[w * 16 + lane_lo];
    float bs_v  = (w < 2) ? ((const float*)(ws + BS_OFF))[w * 16 + lane_lo] : 0.f;

    #pragma unroll
    for (int i = 0; i < 4; ++i) {
        int r = w * 4 + i;
        float s1 = xa[i].x + xa[i].y + xa[i].z + xa[i].w + xb[i].x + xb[i].y + xb[i].z + xb[i].w;
        float s2 = xa[i].x*xa[i].x + xa[i].y*xa[i].y + xa[i].z*xa[i].z + xa[i].w*xa[i].w
                 + xb[i].x*xb[i].x + xb[i].y*xb[i].y + xb[i].z*xb[i].z + xb[i].w*xb[i].w;
        #pragma unroll
        for (int m = 1; m < 64; m <<= 1) {
            s1 += __shfl_xor(s1, m);
            s2 += __shfl_xor(s2, m);
        }
        float mu = s1 * (1.f / 512.f);
        float var = s2 * (1.f / 512.f) - mu * mu;
        float rs = rsqrtf(var + 1e-5f);
        float ya0 = (xa[i].x - mu) * rs * g0.x + q0.x;
        float ya1 = (xa[i].y - mu) * rs * g0.y + q0.y;
        float ya2 = (xa[i].z - mu) * rs * g0.z + q0.z;
        float ya3 = (xa[i].w - mu) * rs * g0.w + q0.w;
        float yb0 = (xb[i].x - mu) * rs * g1.x + q1.x;
        float yb1 = (xb[i].y - mu) * rs * g1.y + q1.y;
        float yb2 = (xb[i].z - mu) * rs * g1.z + q1.z;
        float yb3 = (xb[i].w - mu) * rs * g1.w + q1.w;
        unsigned long long pa =
            (unsigned long long)f2bf(ya0) | ((unsigned long long)f2bf(ya1) << 16) |
            ((unsigned long long)f2bf(ya2) << 32) | ((unsigned long long)f2bf(ya3) << 48);
        unsigned long long pb =
            (unsigned long long)f2bf(yb0) | ((unsigned long long)f2bf(yb1) << 16) |
            ((unsigned long long)f2bf(yb2) << 32) | ((unsigned long long)f2bf(yb3) << 48);
        int sw = (r & 7) << 4;
        *(unsigned long long*)(smem + M_A + ((r * 1024 + l * 8) ^ sw)) = pa;
        *(unsigned long long*)(smem + M_A + ((r * 1024 + 512 + l * 8) ^ sw)) = pb;
    }
    __syncthreads();                                     // barrier 1

    // ===== Phase 2: MFMA GEMM, 2-deep pipelined =====
    int swa = (l & 7) << 4;
    int ab0 = lane_lo * 1024 + (lane_hi << 4);
    int ab1 = (16 + lane_lo) * 1024 + (lane_hi << 4);

    floatx4 acc[3][2];
    #pragma unroll
    for (int i = 0; i < 3; ++i)
        #pragma unroll
        for (int mt = 0; mt < 2; ++mt)
            acc[i][mt] = (floatx4){0.f, 0.f, 0.f, 0.f};

    bfrag_t acur0, acur1, anxt0, anxt1, afar0, afar1;
    acur0 = *(const bfrag_t*)(smem + M_A + (ab0 ^ swa));
    acur1 = *(const bfrag_t*)(smem + M_A + (ab1 ^ swa));
    anxt0 = *(const bfrag_t*)(smem + M_A + ((ab0 + 64) ^ swa));
    anxt1 = *(const bfrag_t*)(smem + M_A + ((ab1 + 64) ^ swa));

    for (int kt = 0; kt < 16; ++kt) {
        if (kt < 14) {
            int ko = (kt + 2) * 64;
            afar0 = *(const bfrag_t*)(smem + M_A + ((ab0 + ko) ^ swa));
            afar1 = *(const bfrag_t*)(smem + M_A + ((ab1 + ko) ^ swa));
            #pragma unroll
            for (int i = 0; i < 3; ++i)
                if (i < nf) bfar[i] = wf[((kt + 2) * 18 + nts[i]) * 64 + l];
        }
        #pragma unroll
        for (int i = 0; i < 3; ++i) {
            if (i < nf) {
                acc[i][0] = __builtin_amdgcn_mfma_f32_16x16x32_bf16(acur0, bcur[i], acc[i][0], 0, 0, 0);
                acc[i][1] = __builtin_amdgcn_mfma_f32_16x16x32_bf16(acur1, bcur[i], acc[i][1], 0, 0, 0);
            }
        }
        acur0 = anxt0; acur1 = anxt1; anxt0 = afar0; anxt1 = afar1;
        #pragma unroll
        for (int i = 0; i < 3; ++i)
            if (i < nf) { bcur[i] = bnxt[i]; bnxt[i] = bfar[i]; }
    }

    // ===== Phase 3: epilogue =====
    {
        #pragma unroll
        for (int i = 0; i < 3; ++i) {
            if (i < nf) {
                int n = nts[i] * 16 + lane_lo;
                float bias = (i == 0) ? bin_v : ((i == 1) ? bu_v : bs_v);
                #pragma unroll
                for (int mt = 0; mt < 2; ++mt) {
                    #pragma unroll
                    for (int r4 = 0; r4 < 4; ++r4) {
                        int row = mt * 16 + lane_hi * 4 + r4;
                        float v = acc[i][mt][r4] + bias;
                        if (i == 0) {
                            int addr = M_XPF +
                                (((n >> 4) * 64 + ((n & 15) | ((row >> 3) << 4))) * 8
                                 + (row & 7)) * 2;
                            *(unsigned short*)(smem + addr) = f2bf(v);
                        } else if (i == 1) {
                            int d = n - 128;
                            *(float*)(smem + M_U + (row * 128 + d) * 4) = v;
                        } else {
                            int s = n - 256;
                            *(float*)(smem + M_SC + (row * 32 + s) * 4) = v;
                        }
                    }
                }
            }
        }
    }
    __syncthreads();                                     // barrier 2

    bfrag_t bm = ((const bfrag_t*)(ws + MEMFRAG_OFF))[w * 64 + l];
    bfrag_t bx = *(const bfrag_t*)(smem + M_XPF + (w * 64 + l) * 16);
    int sbase = w * 4;
    const float* gb = (const float*)(ws + GB_OFF);
    float gbr0[4], gbr1[4];
    #pragma unroll
    for (int si = 0; si < 4; ++si) {
        gbr0[si] = gb[(sbase + si) * 128 + l];
        gbr1[si] = gb[(sbase + si) * 128 + l + 64];
    }

    // ===== Phase 4: softmax =====
    #pragma unroll
    for (int i = 0; i < 4; ++i) {
        int r = w * 4 + i;
        int s = l & 31;
        float sc = *(const float*)(smem + M_SC + (r * 32 + s) * 4);
        float mx = sc;
        #pragma unroll
        for (int m = 1; m < 32; m <<= 1) mx = fmaxf(mx, __shfl_xor(mx, m));
        float e = __expf(sc - mx);
        float sum = e;
        #pragma unroll
        for (int m = 1; m < 32; m <<= 1) sum += __shfl_xor(sum, m);
        float p = e * __builtin_amdgcn_rcpf(sum);
        if (l < 32) {
            unsigned short pb = f2bf(p);
            *(unsigned short*)(smem + M_PR +
                (((r >> 4) * 64 + ((r & 15) + 16 * (s >> 3))) * 8 + (s & 7)) * 2) = pb;
            *(unsigned short*)(smem + M_PRT +
                (((s >> 4) * 64 + ((s & 15) + 16 * (r >> 3))) * 8 + (r & 7)) * 2) = pb;
        }
    }
    __syncthreads();                                     // barrier 3

    // ===== Phase 5: read-GEMM + write-GEMM =====
    float* pw = (float*)(ws + ACC_OFF + (size_t)blockIdx.x * 32768);
    {
        bfrag_t pa0 = *(const bfrag_t*)(smem + M_PR + l * 16);
        bfrag_t pa1 = *(const bfrag_t*)(smem + M_PR + 1024 + l * 16);
        bfrag_t pat0 = *(const bfrag_t*)(smem + M_PRT + l * 16);
        bfrag_t pat1 = *(const bfrag_t*)(smem + M_PRT + 1024 + l * 16);

        floatx4 r0 = (floatx4){0.f, 0.f, 0.f, 0.f};
        floatx4 r1 = (floatx4){0.f, 0.f, 0.f, 0.f};
        r0 = __builtin_amdgcn_mfma_f32_16x16x32_bf16(pa0, bm, r0, 0, 0, 0);
        r1 = __builtin_amdgcn_mfma_f32_16x16x32_bf16(pa1, bm, r1, 0, 0, 0);
        floatx4 w0 = (floatx4){0.f, 0.f, 0.f, 0.f};
        floatx4 w1 = (floatx4){0.f, 0.f, 0.f, 0.f};
        w0 = __builtin_amdgcn_mfma_f32_16x16x32_bf16(pat0, bx, w0, 0, 0, 0);
        w1 = __builtin_amdgcn_mfma_f32_16x16x32_bf16(pat1, bx, w1, 0, 0, 0);

        int nc = w * 16 + lane_lo;
        #pragma unroll
        for (int r4 = 0; r4 < 4; ++r4) {
            int row = lane_hi * 4 + r4;
            out[(size_t)(row_base + row) * 128 + nc] = r0[r4];
            out[(size_t)(row_base + row + 16) * 128 + nc] = r1[r4];
            pw[row * 128 + nc] = w0[r4];
            pw[(row + 16) * 128 + nc] = w1[r4];
        }
    }

    // ===== Phase 6: gate sigmoids -> partial accg =====
    {
        float* pg = pw + 4096;
        float ag0[4], ag1[4];
        #pragma unroll
        for (int si = 0; si < 4; ++si) { ag0[si] = 0.f; ag1[si] = 0.f; }
        #pragma unroll 4
        for (int r = 0; r < 32; ++r) {
            float uv0 = *(const float*)(smem + M_U + (r * 128 + l) * 4);
            float uv1 = *(const float*)(smem + M_U + (r * 128 + l + 64) * 4);
            #pragma unroll
            for (int si = 0; si < 4; ++si) {
                ag0[si] += sigm(gbr0[si] + uv0);
                ag1[si] += sigm(gbr1[si] + uv1);
            }
        }
        #pragma unroll
        for (int si = 0; si < 4; ++si) {
            pg[(sbase + si) * 128 + l]      = ag0[si];
            pg[(sbase + si) * 128 + l + 64] = ag1[si];
        }
    }
}

// ---------------- finalize: reduce 512 partials (float4) -> new_memory ----------------
__global__ __launch_bounds__(512) void fin_kernel(
    const float* __restrict__ memv, const unsigned char* __restrict__ ws,
    float* __restrict__ out2)
{
    __shared__ float4 red[2][32][16];
    int b = blockIdx.x, t = threadIdx.x;
    int f4 = t & 15, ch = t >> 4;
    const float* base = (const float*)(ws + ACC_OFF);
    int e4 = b * 16 + f4;

    float4 aw = {0.f, 0.f, 0.f, 0.f}, ag = {0.f, 0.f, 0.f, 0.f};
    #pragma unroll 4
    for (int c = ch * 16; c < ch * 16 + 16; ++c) {
        float4 a = ((const float4*)(base + (size_t)c * 8192))[e4];
        float4 g = ((const float4*)(base + (size_t)c * 8192 + 4096))[e4];
        aw.x += a.x; aw.y += a.y; aw.z += a.z; aw.w += a.w;
        ag.x += g.x; ag.y += g.y; ag.z += g.z; ag.w += g.w;
    }
    red[0][ch][f4] = aw;
    red[1][ch][f4] = ag;
    __syncthreads();
    if (t < 16) {
        float4 a = {0.f, 0.f, 0.f, 0.f}, g = {0.f, 0.f, 0.f, 0.f};
        #pragma unroll
        for (int c = 0; c < 32; ++c) {
            float4 ra = red[0][c][t], rg = red[1][c][t];
            a.x += ra.x; a.y += ra.y; a.z += ra.z; a.w += ra.w;
            g.x += rg.x; g.y += rg.y; g.z += rg.z; g.w += rg.w;
        }
        const float4 m4 = ((const float4*)memv)[b * 16 + t];
        float4 o;
        float s = 1.f / 16384.f;
        float gx = g.x * s, gy = g.y * s, gz = g.z * s, gw = g.w * s;
        o.x = m4.x * (1.f - gx) + a.x * s * gx;
        o.y = m4.y * (1.f - gy) + a.y * s * gy;
        o.z = m4.z * (1.f - gz) + a.z * s * gz;
        o.w = m4.w * (1.f - gw) + a.w * s * gw;
        ((float4*)out2)[b * 16 + t] = o;
    }
}

// ---------------- launcher ----------------
// MEASUREMENT ROUND: main_kernel launched TWICE (idempotent — pure overwrites of
// out rows and ws partials from prep-written inputs). dur_us delta vs R9 (49.1)
// isolates main+gap.
extern "C" void kernel_launch(void* const* d_in, const int* in_sizes, int n_in,
                              void* d_out, int out_size, void* d_ws, size_t ws_size,
                              hipStream_t stream)
{
    (void)in_sizes; (void)n_in; (void)out_size; (void)ws_size;
    const float* x      = (const float*)d_in[0];
    const float* memv   = (const float*)d_in[1];
    const float* ln_g   = (const float*)d_in[2];
    const float* ln_b   = (const float*)d_in[3];
    const float* w_in   = (const float*)d_in[4];
    const float* b_in   = (const float*)d_in[5];
    const float* w_gate = (const float*)d_in[6];
    const float* b_gate = (const float*)d_in[7];
    float* out = (float*)d_out;
    unsigned char* ws = (unsigned char*)d_ws;

    hipLaunchKernelGGL(prep_kernel, dim3(273), dim3(256), 0, stream,
                       memv, w_in, b_in, w_gate, b_gate, ws);
    hipLaunchKernelGGL(main_kernel, dim3(NBLK), dim3(512), 0, stream,
                       x, ln_g, ln_b, b_in, ws, out);
    hipLaunchKernelGGL(main_kernel, dim3(NBLK), dim3(512), 0, stream,
                       x, ln_g, ln_b, b_in, ws, out);
    hipLaunchKernelGGL(fin_kernel, dim3(64), dim3(512), 0, stream,
                       memv, ws, out + 2097152);
}

// Round 12
// 52.008 us; speedup vs baseline: 1.5342x; 1.5342x over previous
//
#include <hip/hip_runtime.h>
#include <stdint.h>

typedef __attribute__((ext_vector_type(8))) short bfrag_t;    // 8 bf16
typedef __attribute__((ext_vector_type(4))) float floatx4;    // MFMA acc
typedef __attribute__((ext_vector_type(8))) unsigned short ushort8_t;

// ---------------- ws layout (bytes) ----------------
#define WFRAG_OFF   0            // bf16 [16kt][18nt][64lane][8j] = 294912
#define GB_OFF      294912       // f32 [32][128]
#define BU_OFF      311296       // f32 [128]
#define BS_OFF      311808       // f32 [32]
#define MEMFRAG_OFF 311936       // bf16 frag [8nt][64][8] = 8192
#define ACC_OFF     327680       // 512 x (accw[4096] | accg[4096]) bf16 = 8 MiB
#define NBLK        512

// ---------------- main LDS layout (bytes), NO overlay, 64 KiB ----------------
#define M_A     0        // bf16 swizzled A-tile [32r][512k] = 32768
#define M_XPF   32768    // bf16 B-frag [8nt][64][8] (k=rows) = 8192
#define M_U     40960    // f32 [32][128] = 16384
#define M_SC    57344    // f32 [32][32] = 4096
#define M_PR    61440    // bf16 A-frag [2mt][64][8] (probs, k=s) = 2048
#define M_PRT   63488    // bf16 A-frag [2mt][64][8] (probsT, k=r) = 2048
#define M_LDS   65536

__device__ __forceinline__ unsigned short f2bf(float f) {
    unsigned u = __float_as_uint(f);
    u += 0x7fffu + ((u >> 16) & 1u);
    return (unsigned short)(u >> 16);
}
__device__ __forceinline__ float bf2f(unsigned short h) {
    return __uint_as_float(((unsigned)h) << 16);
}
__device__ __forceinline__ float sigm(float v) {
    return __builtin_amdgcn_rcpf(1.0f + __expf(-v));
}
__device__ __forceinline__ void writefrag(unsigned short* wf, int k, int n, float v) {
    int kt = k >> 5, kk = k & 31;
    int lane = (n & 15) | ((kk >> 3) << 4);
    wf[(((kt * 18) + (n >> 4)) * 64 + lane) * 8 + (kk & 7)] = f2bf(v);
}

// ---------------- prep: frag weights, gate base, biases, mem frags ----------------
__global__ __launch_bounds__(256) void prep_kernel(
    const float* __restrict__ memv, const float* __restrict__ w_in,
    const float* __restrict__ b_in, const float* __restrict__ w_gate,
    const float* __restrict__ b_gate, unsigned char* __restrict__ ws)
{
    int bid = blockIdx.x, t = threadIdx.x;
    unsigned short* wfrag = (unsigned short*)(ws + WFRAG_OFF);
    const float* wg2 = w_gate + 128 * 128;

    if (bid < 256) {
        __shared__ float wrow[2][128];
        int k0 = bid * 2;
        wrow[t >> 7][t & 127] = w_in[(size_t)(k0 + (t >> 7)) * 128 + (t & 127)];
        __syncthreads();
        for (int kl = 0; kl < 2; ++kl) {
            int k = k0 + kl;
            float v;
            if (t < 128) {
                v = wrow[kl][t];
            } else {
                int d = t - 128;
                float acc = 0.f;
                #pragma unroll 16
                for (int j = 0; j < 128; ++j) acc += wrow[kl][j] * wg2[j * 128 + d];
                v = acc;
            }
            writefrag(wfrag, k, t, v);
            if (t < 32) {
                float acc = 0.f;
                #pragma unroll 16
                for (int d = 0; d < 128; ++d) acc += wrow[kl][d] * memv[t * 128 + d];
                writefrag(wfrag, k, 256 + t, acc);
            }
        }
    } else if (bid < 272) {
        int idx = (bid - 256) * 256 + t;
        int s = idx >> 7, d = idx & 127;
        float acc = b_gate[d];
        #pragma unroll 16
        for (int k = 0; k < 128; ++k) acc += memv[s * 128 + k] * w_gate[k * 128 + d];
        ((float*)(ws + GB_OFF))[idx] = acc;
    } else {
        if (t < 128) {
            float acc = 0.f;
            #pragma unroll 16
            for (int j = 0; j < 128; ++j) acc += b_in[j] * wg2[j * 128 + t];
            ((float*)(ws + BU_OFF))[t] = acc;
        }
        if (t < 32) {
            float acc = 0.f;
            #pragma unroll 16
            for (int d = 0; d < 128; ++d) acc += b_in[d] * memv[t * 128 + d];
            ((float*)(ws + BS_OFF))[t] = acc;
        }
        unsigned short* mfr = (unsigned short*)(ws + MEMFRAG_OFF);
        for (int idx = t; idx < 4096; idx += 256) {
            int s = idx >> 7, d = idx & 127;
            mfr[((d >> 4) * 64 + ((d & 15) | (((s >> 3) & 3) << 4))) * 8 + (s & 7)]
                = f2bf(memv[idx]);
        }
    }
}

// ---------------- main: 512 blocks x 512 threads, 32 rows/block ----------------
__global__ __launch_bounds__(512, 4) void main_kernel(
    const float* __restrict__ x,
    const float* __restrict__ ln_g, const float* __restrict__ ln_b,
    const float* __restrict__ b_in, unsigned char* __restrict__ ws,
    float* __restrict__ out)
{
    __shared__ char smem[M_LDS] __attribute__((aligned(16)));

    int tid = threadIdx.x;
    int w = tid >> 6, l = tid & 63;          // 8 waves
    int lane_lo = l & 15, lane_hi = l >> 4;
    int row_base = blockIdx.x * 32;

    int nf = (w < 2) ? 3 : 2;
    int nts[3] = {w, w + 8, 16 + w};
    const bfrag_t* wf = (const bfrag_t*)(ws + WFRAG_OFF);

    // ===== Phase 1: LayerNorm -> swizzled bf16 A tile [32][512] =====
    const float4* x4 = (const float4*)x;
    float4 g0 = ((const float4*)ln_g)[l];
    float4 g1 = ((const float4*)ln_g)[l + 64];
    float4 q0 = ((const float4*)ln_b)[l];
    float4 q1 = ((const float4*)ln_b)[l + 64];

    float4 xa[4], xb[4];
    #pragma unroll
    for (int i = 0; i < 4; ++i) {
        int r = w * 4 + i;
        xa[i] = x4[(size_t)(row_base + r) * 128 + l];
        xb[i] = x4[(size_t)(row_base + r) * 128 + 64 + l];
    }

    bfrag_t bcur[3], bnxt[3], bfar[3];
    #pragma unroll
    for (int i = 0; i < 3; ++i) {
        if (i < nf) {
            bcur[i] = wf[(0 * 18 + nts[i]) * 64 + l];
            bnxt[i] = wf[(1 * 18 + nts[i]) * 64 + l];
        }
    }
    float bin_v = b_in[w * 16 + lane_lo];
    float bu_v  = ((const float*)(ws + BU_OFF))[w * 16 + lane_lo];
    float bs_v  = (w < 2) ? ((const float*)(ws + BS_OFF))[w * 16 + lane_lo] : 0.f;

    #pragma unroll
    for (int i = 0; i < 4; ++i) {
        int r = w * 4 + i;
        float s1 = xa[i].x + xa[i].y + xa[i].z + xa[i].w + xb[i].x + xb[i].y + xb[i].z + xb[i].w;
        float s2 = xa[i].x*xa[i].x + xa[i].y*xa[i].y + xa[i].z*xa[i].z + xa[i].w*xa[i].w
                 + xb[i].x*xb[i].x + xb[i].y*xb[i].y + xb[i].z*xb[i].z + xb[i].w*xb[i].w;
        #pragma unroll
        for (int m = 1; m < 64; m <<= 1) {
            s1 += __shfl_xor(s1, m);
            s2 += __shfl_xor(s2, m);
        }
        float mu = s1 * (1.f / 512.f);
        float var = s2 * (1.f / 512.f) - mu * mu;
        float rs = rsqrtf(var + 1e-5f);
        float ya0 = (xa[i].x - mu) * rs * g0.x + q0.x;
        float ya1 = (xa[i].y - mu) * rs * g0.y + q0.y;
        float ya2 = (xa[i].z - mu) * rs * g0.z + q0.z;
        float ya3 = (xa[i].w - mu) * rs * g0.w + q0.w;
        float yb0 = (xb[i].x - mu) * rs * g1.x + q1.x;
        float yb1 = (xb[i].y - mu) * rs * g1.y + q1.y;
        float yb2 = (xb[i].z - mu) * rs * g1.z + q1.z;
        float yb3 = (xb[i].w - mu) * rs * g1.w + q1.w;
        unsigned long long pa =
            (unsigned long long)f2bf(ya0) | ((unsigned long long)f2bf(ya1) << 16) |
            ((unsigned long long)f2bf(ya2) << 32) | ((unsigned long long)f2bf(ya3) << 48);
        unsigned long long pb =
            (unsigned long long)f2bf(yb0) | ((unsigned long long)f2bf(yb1) << 16) |
            ((unsigned long long)f2bf(yb2) << 32) | ((unsigned long long)f2bf(yb3) << 48);
        int sw = (r & 7) << 4;
        *(unsigned long long*)(smem + M_A + ((r * 1024 + l * 8) ^ sw)) = pa;
        *(unsigned long long*)(smem + M_A + ((r * 1024 + 512 + l * 8) ^ sw)) = pb;
    }
    __syncthreads();                                     // barrier 1

    // ===== Phase 2: MFMA GEMM, 2-deep pipelined =====
    int swa = (l & 7) << 4;
    int ab0 = lane_lo * 1024 + (lane_hi << 4);
    int ab1 = (16 + lane_lo) * 1024 + (lane_hi << 4);

    floatx4 acc[3][2];
    #pragma unroll
    for (int i = 0; i < 3; ++i)
        #pragma unroll
        for (int mt = 0; mt < 2; ++mt)
            acc[i][mt] = (floatx4){0.f, 0.f, 0.f, 0.f};

    bfrag_t acur0, acur1, anxt0, anxt1, afar0, afar1;
    acur0 = *(const bfrag_t*)(smem + M_A + (ab0 ^ swa));
    acur1 = *(const bfrag_t*)(smem + M_A + (ab1 ^ swa));
    anxt0 = *(const bfrag_t*)(smem + M_A + ((ab0 + 64) ^ swa));
    anxt1 = *(const bfrag_t*)(smem + M_A + ((ab1 + 64) ^ swa));

    for (int kt = 0; kt < 16; ++kt) {
        if (kt < 14) {
            int ko = (kt + 2) * 64;
            afar0 = *(const bfrag_t*)(smem + M_A + ((ab0 + ko) ^ swa));
            afar1 = *(const bfrag_t*)(smem + M_A + ((ab1 + ko) ^ swa));
            #pragma unroll
            for (int i = 0; i < 3; ++i)
                if (i < nf) bfar[i] = wf[((kt + 2) * 18 + nts[i]) * 64 + l];
        }
        #pragma unroll
        for (int i = 0; i < 3; ++i) {
            if (i < nf) {
                acc[i][0] = __builtin_amdgcn_mfma_f32_16x16x32_bf16(acur0, bcur[i], acc[i][0], 0, 0, 0);
                acc[i][1] = __builtin_amdgcn_mfma_f32_16x16x32_bf16(acur1, bcur[i], acc[i][1], 0, 0, 0);
            }
        }
        acur0 = anxt0; acur1 = anxt1; anxt0 = afar0; anxt1 = afar1;
        #pragma unroll
        for (int i = 0; i < 3; ++i)
            if (i < nf) { bcur[i] = bnxt[i]; bnxt[i] = bfar[i]; }
    }

    // ===== Phase 3: epilogue =====
    {
        #pragma unroll
        for (int i = 0; i < 3; ++i) {
            if (i < nf) {
                int n = nts[i] * 16 + lane_lo;
                float bias = (i == 0) ? bin_v : ((i == 1) ? bu_v : bs_v);
                #pragma unroll
                for (int mt = 0; mt < 2; ++mt) {
                    #pragma unroll
                    for (int r4 = 0; r4 < 4; ++r4) {
                        int row = mt * 16 + lane_hi * 4 + r4;
                        float v = acc[i][mt][r4] + bias;
                        if (i == 0) {
                            int addr = M_XPF +
                                (((n >> 4) * 64 + ((n & 15) | ((row >> 3) << 4))) * 8
                                 + (row & 7)) * 2;
                            *(unsigned short*)(smem + addr) = f2bf(v);
                        } else if (i == 1) {
                            int d = n - 128;
                            *(float*)(smem + M_U + (row * 128 + d) * 4) = v;
                        } else {
                            int s = n - 256;
                            *(float*)(smem + M_SC + (row * 32 + s) * 4) = v;
                        }
                    }
                }
            }
        }
    }
    __syncthreads();                                     // barrier 2: SC/U/XPF ready

    // pre-issue phase-5 operands
    bfrag_t bm = ((const bfrag_t*)(ws + MEMFRAG_OFF))[w * 64 + l];
    bfrag_t bx = *(const bfrag_t*)(smem + M_XPF + (w * 64 + l) * 16);
    int sbase = w * 4;
    const float* gb = (const float*)(ws + GB_OFF);
    float gbr0[4], gbr1[4];
    #pragma unroll
    for (int si = 0; si < 4; ++si) {
        gbr0[si] = gb[(sbase + si) * 128 + l];
        gbr1[si] = gb[(sbase + si) * 128 + l + 64];
    }

    // ===== gate chunk 1: rows 0..15 (trans work before softmax) =====
    float ag0[4], ag1[4];
    #pragma unroll
    for (int si = 0; si < 4; ++si) { ag0[si] = 0.f; ag1[si] = 0.f; }
    #pragma unroll 4
    for (int r = 0; r < 16; ++r) {
        float uv0 = *(const float*)(smem + M_U + (r * 128 + l) * 4);
        float uv1 = *(const float*)(smem + M_U + (r * 128 + l + 64) * 4);
        #pragma unroll
        for (int si = 0; si < 4; ++si) {
            ag0[si] += sigm(gbr0[si] + uv0);
            ag1[si] += sigm(gbr1[si] + uv1);
        }
    }

    // ===== Phase 4: softmax (4 rows/wave) =====
    #pragma unroll
    for (int i = 0; i < 4; ++i) {
        int r = w * 4 + i;
        int s = l & 31;
        float sc = *(const float*)(smem + M_SC + (r * 32 + s) * 4);
        float mx = sc;
        #pragma unroll
        for (int m = 1; m < 32; m <<= 1) mx = fmaxf(mx, __shfl_xor(mx, m));
        float e = __expf(sc - mx);
        float sum = e;
        #pragma unroll
        for (int m = 1; m < 32; m <<= 1) sum += __shfl_xor(sum, m);
        float p = e * __builtin_amdgcn_rcpf(sum);
        if (l < 32) {
            unsigned short pb = f2bf(p);
            *(unsigned short*)(smem + M_PR +
                (((r >> 4) * 64 + ((r & 15) + 16 * (s >> 3))) * 8 + (s & 7)) * 2) = pb;
            *(unsigned short*)(smem + M_PRT +
                (((s >> 4) * 64 + ((s & 15) + 16 * (r >> 3))) * 8 + (r & 7)) * 2) = pb;
        }
    }
    __syncthreads();                                     // barrier 3

    // ===== Phase 5: read-GEMM (rc -> global) + write-GEMM (bf16 partial -> ws) =====
    unsigned short* pwh = (unsigned short*)(ws + ACC_OFF + (size_t)blockIdx.x * 16384);
    {
        bfrag_t pa0 = *(const bfrag_t*)(smem + M_PR + l * 16);
        bfrag_t pa1 = *(const bfrag_t*)(smem + M_PR + 1024 + l * 16);
        bfrag_t pat0 = *(const bfrag_t*)(smem + M_PRT + l * 16);
        bfrag_t pat1 = *(const bfrag_t*)(smem + M_PRT + 1024 + l * 16);

        floatx4 r0 = (floatx4){0.f, 0.f, 0.f, 0.f};
        floatx4 r1 = (floatx4){0.f, 0.f, 0.f, 0.f};
        r0 = __builtin_amdgcn_mfma_f32_16x16x32_bf16(pa0, bm, r0, 0, 0, 0);
        r1 = __builtin_amdgcn_mfma_f32_16x16x32_bf16(pa1, bm, r1, 0, 0, 0);
        floatx4 w0 = (floatx4){0.f, 0.f, 0.f, 0.f};
        floatx4 w1 = (floatx4){0.f, 0.f, 0.f, 0.f};
        w0 = __builtin_amdgcn_mfma_f32_16x16x32_bf16(pat0, bx, w0, 0, 0, 0);
        w1 = __builtin_amdgcn_mfma_f32_16x16x32_bf16(pat1, bx, w1, 0, 0, 0);

        int nc = w * 16 + lane_lo;
        #pragma unroll
        for (int r4 = 0; r4 < 4; ++r4) {
            int row = lane_hi * 4 + r4;
            out[(size_t)(row_base + row) * 128 + nc] = r0[r4];
            out[(size_t)(row_base + row + 16) * 128 + nc] = r1[r4];
            pwh[row * 128 + nc] = f2bf(w0[r4]);
            pwh[(row + 16) * 128 + nc] = f2bf(w1[r4]);
        }
    }

    // ===== gate chunk 2: rows 16..31, then bf16 partial store =====
    {
        #pragma unroll 4
        for (int r = 16; r < 32; ++r) {
            float uv0 = *(const float*)(smem + M_U + (r * 128 + l) * 4);
            float uv1 = *(const float*)(smem + M_U + (r * 128 + l + 64) * 4);
            #pragma unroll
            for (int si = 0; si < 4; ++si) {
                ag0[si] += sigm(gbr0[si] + uv0);
                ag1[si] += sigm(gbr1[si] + uv1);
            }
        }
        unsigned short* pgh = pwh + 4096;
        #pragma unroll
        for (int si = 0; si < 4; ++si) {
            pgh[(sbase + si) * 128 + l]      = f2bf(ag0[si]);
            pgh[(sbase + si) * 128 + l + 64] = f2bf(ag1[si]);
        }
    }
}

// ---------------- finalize: 256 blocks x 512 threads; thread t owns copy t ----------------
__global__ __launch_bounds__(512) void fin_kernel(
    const float* __restrict__ memv, const unsigned char* __restrict__ ws,
    float* __restrict__ out2)
{
    __shared__ float red[8][32];
    __shared__ float fsum[32];
    int b = blockIdx.x, t = threadIdx.x;
    int wv = t >> 6, ln = t & 63;
    int col0 = b * 16;

    const unsigned short* cb = (const unsigned short*)(ws + ACC_OFF) + (size_t)t * 8192;
    ushort8_t a0 = *(const ushort8_t*)(cb + col0);
    ushort8_t a1 = *(const ushort8_t*)(cb + col0 + 8);
    ushort8_t gg0 = *(const ushort8_t*)(cb + 4096 + col0);
    ushort8_t gg1 = *(const ushort8_t*)(cb + 4096 + col0 + 8);

    float v[32];
    #pragma unroll
    for (int i = 0; i < 8; ++i) {
        v[i]      = bf2f(a0[i]);
        v[8 + i]  = bf2f(a1[i]);
        v[16 + i] = bf2f(gg0[i]);
        v[24 + i] = bf2f(gg1[i]);
    }
    #pragma unroll
    for (int m = 1; m < 64; m <<= 1) {
        #pragma unroll
        for (int i = 0; i < 32; ++i) v[i] += __shfl_xor(v[i], m);
    }
    if (ln == 0) {
        #pragma unroll
        for (int i = 0; i < 32; ++i) red[wv][i] = v[i];
    }
    __syncthreads();
    if (t < 32) {
        float s = 0.f;
        #pragma unroll
        for (int c = 0; c < 8; ++c) s += red[c][t];
        fsum[t] = s;
    }
    __syncthreads();
    if (t < 16) {
        float a = fsum[t] * (1.f / 16384.f);
        float g = fsum[16 + t] * (1.f / 16384.f);
        int i = col0 + t;
        out2[i] = memv[i] * (1.f - g) + a * g;
    }
}

// ---------------- launcher ----------------
extern "C" void kernel_launch(void* const* d_in, const int* in_sizes, int n_in,
                              void* d_out, int out_size, void* d_ws, size_t ws_size,
                              hipStream_t stream)
{
    (void)in_sizes; (void)n_in; (void)out_size; (void)ws_size;
    const float* x      = (const float*)d_in[0];
    const float* memv   = (const float*)d_in[1];
    const float* ln_g   = (const float*)d_in[2];
    const float* ln_b   = (const float*)d_in[3];
    const float* w_in   = (const float*)d_in[4];
    const float* b_in   = (const float*)d_in[5];
    const float* w_gate = (const float*)d_in[6];
    const float* b_gate = (const float*)d_in[7];
    float* out = (float*)d_out;
    unsigned char* ws = (unsigned char*)d_ws;

    hipLaunchKernelGGL(prep_kernel, dim3(273), dim3(256), 0, stream,
                       memv, w_in, b_in, w_gate, b_gate, ws);
    hipLaunchKernelGGL(main_kernel, dim3(NBLK), dim3(512), 0, stream,
                       x, ln_g, ln_b, b_in, ws, out);
    hipLaunchKernelGGL(fin_kernel, dim3(256), dim3(512), 0, stream,
                       memv, ws, out + 2097152);
}

// Round 13
// 51.921 us; speedup vs baseline: 1.5368x; 1.0017x over previous
//
#include <hip/hip_runtime.h>
#include <stdint.h>

typedef __attribute__((ext_vector_type(8))) short bfrag_t;    // 8 bf16
typedef __attribute__((ext_vector_type(4))) float floatx4;    // MFMA acc
typedef __attribute__((ext_vector_type(8))) unsigned short ushort8_t;

// ---------------- ws layout (bytes) ----------------
#define WFRAG_OFF   0            // bf16 [16kt][18nt][64lane][8j] = 294912
#define GB_OFF      294912       // f32 [32][128]
#define BU_OFF      311296       // f32 [128]
#define BS_OFF      311808       // f32 [32]
#define MEMFRAG_OFF 311936       // bf16 frag [8nt][64][8] = 8192
#define ACC_OFF     327680       // 512 x (accw[4096] | accg[4096]) bf16 = 8 MiB
#define NBLK        512

// ---------------- main LDS layout (bytes), NO overlay, 64 KiB ----------------
#define M_A     0        // bf16 swizzled A-tile [32r][512k] = 32768
#define M_XPF   32768    // bf16 B-frag [8nt][64][8] (k=rows) = 8192
#define M_U     40960    // f32 [32][128] = 16384
#define M_SC    57344    // f32 [32][32] = 4096
#define M_PR    61440    // bf16 A-frag [2mt][64][8] (probs, k=s) = 2048
#define M_PRT   63488    // bf16 A-frag [2mt][64][8] (probsT, k=r) = 2048
#define M_LDS   65536

__device__ __forceinline__ unsigned short f2bf(float f) {
    unsigned u = __float_as_uint(f);
    u += 0x7fffu + ((u >> 16) & 1u);
    return (unsigned short)(u >> 16);
}
__device__ __forceinline__ float bf2f(unsigned short h) {
    return __uint_as_float(((unsigned)h) << 16);
}
__device__ __forceinline__ float sigm(float v) {
    return __builtin_amdgcn_rcpf(1.0f + __expf(-v));
}
__device__ __forceinline__ void writefrag(unsigned short* wf, int k, int n, float v) {
    int kt = k >> 5, kk = k & 31;
    int lane = (n & 15) | ((kk >> 3) << 4);
    wf[(((kt * 18) + (n >> 4)) * 64 + lane) * 8 + (kk & 7)] = f2bf(v);
}

// ---------------- prep: frag weights, gate base, biases, mem frags ----------------
__global__ __launch_bounds__(256) void prep_kernel(
    const float* __restrict__ memv, const float* __restrict__ w_in,
    const float* __restrict__ b_in, const float* __restrict__ w_gate,
    const float* __restrict__ b_gate, unsigned char* __restrict__ ws)
{
    int bid = blockIdx.x, t = threadIdx.x;
    unsigned short* wfrag = (unsigned short*)(ws + WFRAG_OFF);
    const float* wg2 = w_gate + 128 * 128;

    if (bid < 256) {
        __shared__ float wrow[2][128];
        int k0 = bid * 2;
        wrow[t >> 7][t & 127] = w_in[(size_t)(k0 + (t >> 7)) * 128 + (t & 127)];
        __syncthreads();
        for (int kl = 0; kl < 2; ++kl) {
            int k = k0 + kl;
            float v;
            if (t < 128) {
                v = wrow[kl][t];
            } else {
                int d = t - 128;
                float acc = 0.f;
                #pragma unroll 16
                for (int j = 0; j < 128; ++j) acc += wrow[kl][j] * wg2[j * 128 + d];
                v = acc;
            }
            writefrag(wfrag, k, t, v);
            if (t < 32) {
                float acc = 0.f;
                #pragma unroll 16
                for (int d = 0; d < 128; ++d) acc += wrow[kl][d] * memv[t * 128 + d];
                writefrag(wfrag, k, 256 + t, acc);
            }
        }
    } else if (bid < 272) {
        int idx = (bid - 256) * 256 + t;
        int s = idx >> 7, d = idx & 127;
        float acc = b_gate[d];
        #pragma unroll 16
        for (int k = 0; k < 128; ++k) acc += memv[s * 128 + k] * w_gate[k * 128 + d];
        ((float*)(ws + GB_OFF))[idx] = acc;
    } else {
        if (t < 128) {
            float acc = 0.f;
            #pragma unroll 16
            for (int j = 0; j < 128; ++j) acc += b_in[j] * wg2[j * 128 + t];
            ((float*)(ws + BU_OFF))[t] = acc;
        }
        if (t < 32) {
            float acc = 0.f;
            #pragma unroll 16
            for (int d = 0; d < 128; ++d) acc += b_in[d] * memv[t * 128 + d];
            ((float*)(ws + BS_OFF))[t] = acc;
        }
        unsigned short* mfr = (unsigned short*)(ws + MEMFRAG_OFF);
        for (int idx = t; idx < 4096; idx += 256) {
            int s = idx >> 7, d = idx & 127;
            mfr[((d >> 4) * 64 + ((d & 15) | (((s >> 3) & 3) << 4))) * 8 + (s & 7)]
                = f2bf(memv[idx]);
        }
    }
}

// ---------------- main: 512 blocks x 512 threads, 32 rows/block ----------------
__global__ __launch_bounds__(512, 4) void main_kernel(
    const float* __restrict__ x,
    const float* __restrict__ ln_g, const float* __restrict__ ln_b,
    const float* __restrict__ b_in, unsigned char* __restrict__ ws,
    float* __restrict__ out)
{
    __shared__ char smem[M_LDS] __attribute__((aligned(16)));

    int tid = threadIdx.x;
    int w = tid >> 6, l = tid & 63;          // 8 waves
    int lane_lo = l & 15, lane_hi = l >> 4;
    int row_base = blockIdx.x * 32;

    int nf = (w < 2) ? 3 : 2;
    int nts[3] = {w, w + 8, 16 + w};
    const bfrag_t* wf = (const bfrag_t*)(ws + WFRAG_OFF);

    // ===== Phase 1: LayerNorm -> swizzled bf16 A tile [32][512] =====
    const float4* x4 = (const float4*)x;
    float4 g0 = ((const float4*)ln_g)[l];
    float4 g1 = ((const float4*)ln_g)[l + 64];
    float4 q0 = ((const float4*)ln_b)[l];
    float4 q1 = ((const float4*)ln_b)[l + 64];

    float4 xa[4], xb[4];
    #pragma unroll
    for (int i = 0; i < 4; ++i) {
        int r = w * 4 + i;
        xa[i] = x4[(size_t)(row_base + r) * 128 + l];
        xb[i] = x4[(size_t)(row_base + r) * 128 + 64 + l];
    }

    bfrag_t bcur[3], bnxt[3], bfar[3];
    #pragma unroll
    for (int i = 0; i < 3; ++i) {
        if (i < nf) {
            bcur[i] = wf[(0 * 18 + nts[i]) * 64 + l];
            bnxt[i] = wf[(1 * 18 + nts[i]) * 64 + l];
        }
    }
    float bin_v = b_in[w * 16 + lane_lo];
    float bu_v  = ((const float*)(ws + BU_OFF))[w * 16 + lane_lo];
    float bs_v  = (w < 2) ? ((const float*)(ws + BS_OFF))[w * 16 + lane_lo] : 0.f;

    #pragma unroll
    for (int i = 0; i < 4; ++i) {
        int r = w * 4 + i;
        float s1 = xa[i].x + xa[i].y + xa[i].z + xa[i].w + xb[i].x + xb[i].y + xb[i].z + xb[i].w;
        float s2 = xa[i].x*xa[i].x + xa[i].y*xa[i].y + xa[i].z*xa[i].z + xa[i].w*xa[i].w
                 + xb[i].x*xb[i].x + xb[i].y*xb[i].y + xb[i].z*xb[i].z + xb[i].w*xb[i].w;
        #pragma unroll
        for (int m = 1; m < 64; m <<= 1) {
            s1 += __shfl_xor(s1, m);
            s2 += __shfl_xor(s2, m);
        }
        float mu = s1 * (1.f / 512.f);
        float var = s2 * (1.f / 512.f) - mu * mu;
        float rs = rsqrtf(var + 1e-5f);
        float ya0 = (xa[i].x - mu) * rs * g0.x + q0.x;
        float ya1 = (xa[i].y - mu) * rs * g0.y + q0.y;
        float ya2 = (xa[i].z - mu) * rs * g0.z + q0.z;
        float ya3 = (xa[i].w - mu) * rs * g0.w + q0.w;
        float yb0 = (xb[i].x - mu) * rs * g1.x + q1.x;
        float yb1 = (xb[i].y - mu) * rs * g1.y + q1.y;
        float yb2 = (xb[i].z - mu) * rs * g1.z + q1.z;
        float yb3 = (xb[i].w - mu) * rs * g1.w + q1.w;
        unsigned long long pa =
            (unsigned long long)f2bf(ya0) | ((unsigned long long)f2bf(ya1) << 16) |
            ((unsigned long long)f2bf(ya2) << 32) | ((unsigned long long)f2bf(ya3) << 48);
        unsigned long long pb =
            (unsigned long long)f2bf(yb0) | ((unsigned long long)f2bf(yb1) << 16) |
            ((unsigned long long)f2bf(yb2) << 32) | ((unsigned long long)f2bf(yb3) << 48);
        int sw = (r & 7) << 4;
        *(unsigned long long*)(smem + M_A + ((r * 1024 + l * 8) ^ sw)) = pa;
        *(unsigned long long*)(smem + M_A + ((r * 1024 + 512 + l * 8) ^ sw)) = pb;
    }
    __syncthreads();                                     // barrier 1

    // ===== Phase 2: MFMA GEMM, 2-deep pipelined =====
    int swa = (l & 7) << 4;
    int ab0 = lane_lo * 1024 + (lane_hi << 4);
    int ab1 = (16 + lane_lo) * 1024 + (lane_hi << 4);

    floatx4 acc[3][2];
    #pragma unroll
    for (int i = 0; i < 3; ++i)
        #pragma unroll
        for (int mt = 0; mt < 2; ++mt)
            acc[i][mt] = (floatx4){0.f, 0.f, 0.f, 0.f};

    bfrag_t acur0, acur1, anxt0, anxt1, afar0, afar1;
    acur0 = *(const bfrag_t*)(smem + M_A + (ab0 ^ swa));
    acur1 = *(const bfrag_t*)(smem + M_A + (ab1 ^ swa));
    anxt0 = *(const bfrag_t*)(smem + M_A + ((ab0 + 64) ^ swa));
    anxt1 = *(const bfrag_t*)(smem + M_A + ((ab1 + 64) ^ swa));

    for (int kt = 0; kt < 16; ++kt) {
        if (kt < 14) {
            int ko = (kt + 2) * 64;
            afar0 = *(const bfrag_t*)(smem + M_A + ((ab0 + ko) ^ swa));
            afar1 = *(const bfrag_t*)(smem + M_A + ((ab1 + ko) ^ swa));
            #pragma unroll
            for (int i = 0; i < 3; ++i)
                if (i < nf) bfar[i] = wf[((kt + 2) * 18 + nts[i]) * 64 + l];
        }
        #pragma unroll
        for (int i = 0; i < 3; ++i) {
            if (i < nf) {
                acc[i][0] = __builtin_amdgcn_mfma_f32_16x16x32_bf16(acur0, bcur[i], acc[i][0], 0, 0, 0);
                acc[i][1] = __builtin_amdgcn_mfma_f32_16x16x32_bf16(acur1, bcur[i], acc[i][1], 0, 0, 0);
            }
        }
        acur0 = anxt0; acur1 = anxt1; anxt0 = afar0; anxt1 = afar1;
        #pragma unroll
        for (int i = 0; i < 3; ++i)
            if (i < nf) { bcur[i] = bnxt[i]; bnxt[i] = bfar[i]; }
    }

    // ===== Phase 3: epilogue =====
    {
        #pragma unroll
        for (int i = 0; i < 3; ++i) {
            if (i < nf) {
                int n = nts[i] * 16 + lane_lo;
                float bias = (i == 0) ? bin_v : ((i == 1) ? bu_v : bs_v);
                #pragma unroll
                for (int mt = 0; mt < 2; ++mt) {
                    #pragma unroll
                    for (int r4 = 0; r4 < 4; ++r4) {
                        int row = mt * 16 + lane_hi * 4 + r4;
                        float v = acc[i][mt][r4] + bias;
                        if (i == 0) {
                            int addr = M_XPF +
                                (((n >> 4) * 64 + ((n & 15) | ((row >> 3) << 4))) * 8
                                 + (row & 7)) * 2;
                            *(unsigned short*)(smem + addr) = f2bf(v);
                        } else if (i == 1) {
                            int d = n - 128;
                            *(float*)(smem + M_U + (row * 128 + d) * 4) = v;
                        } else {
                            int s = n - 256;
                            *(float*)(smem + M_SC + (row * 32 + s) * 4) = v;
                        }
                    }
                }
            }
        }
    }
    __syncthreads();                                     // barrier 2: SC/U/XPF ready

    // pre-issue phase-5/6 operands; latency hides under softmax
    bfrag_t bm = ((const bfrag_t*)(ws + MEMFRAG_OFF))[w * 64 + l];
    bfrag_t bx = *(const bfrag_t*)(smem + M_XPF + (w * 64 + l) * 16);
    int sbase = w * 4;
    const float* gb = (const float*)(ws + GB_OFF);
    float gbr0[4], gbr1[4];
    #pragma unroll
    for (int si = 0; si < 4; ++si) {
        gbr0[si] = gb[(sbase + si) * 128 + l];
        gbr1[si] = gb[(sbase + si) * 128 + l + 64];
    }

    // ===== Phase 4: softmax (4 rows/wave) =====
    #pragma unroll
    for (int i = 0; i < 4; ++i) {
        int r = w * 4 + i;
        int s = l & 31;
        float sc = *(const float*)(smem + M_SC + (r * 32 + s) * 4);
        float mx = sc;
        #pragma unroll
        for (int m = 1; m < 32; m <<= 1) mx = fmaxf(mx, __shfl_xor(mx, m));
        float e = __expf(sc - mx);
        float sum = e;
        #pragma unroll
        for (int m = 1; m < 32; m <<= 1) sum += __shfl_xor(sum, m);
        float p = e * __builtin_amdgcn_rcpf(sum);
        if (l < 32) {
            unsigned short pb = f2bf(p);
            *(unsigned short*)(smem + M_PR +
                (((r >> 4) * 64 + ((r & 15) + 16 * (s >> 3))) * 8 + (s & 7)) * 2) = pb;
            *(unsigned short*)(smem + M_PRT +
                (((s >> 4) * 64 + ((s & 15) + 16 * (r >> 3))) * 8 + (r & 7)) * 2) = pb;
        }
    }
    __syncthreads();                                     // barrier 3 (last barrier)

    // ===== Phase 5: read-GEMM (rc -> global) + write-GEMM (bf16 partial -> ws) =====
    unsigned short* pwh = (unsigned short*)(ws + ACC_OFF + (size_t)blockIdx.x * 16384);
    {
        bfrag_t pa0 = *(const bfrag_t*)(smem + M_PR + l * 16);
        bfrag_t pa1 = *(const bfrag_t*)(smem + M_PR + 1024 + l * 16);
        bfrag_t pat0 = *(const bfrag_t*)(smem + M_PRT + l * 16);
        bfrag_t pat1 = *(const bfrag_t*)(smem + M_PRT + 1024 + l * 16);

        floatx4 r0 = (floatx4){0.f, 0.f, 0.f, 0.f};
        floatx4 r1 = (floatx4){0.f, 0.f, 0.f, 0.f};
        r0 = __builtin_amdgcn_mfma_f32_16x16x32_bf16(pa0, bm, r0, 0, 0, 0);
        r1 = __builtin_amdgcn_mfma_f32_16x16x32_bf16(pa1, bm, r1, 0, 0, 0);
        floatx4 w0 = (floatx4){0.f, 0.f, 0.f, 0.f};
        floatx4 w1 = (floatx4){0.f, 0.f, 0.f, 0.f};
        w0 = __builtin_amdgcn_mfma_f32_16x16x32_bf16(pat0, bx, w0, 0, 0, 0);
        w1 = __builtin_amdgcn_mfma_f32_16x16x32_bf16(pat1, bx, w1, 0, 0, 0);

        int nc = w * 16 + lane_lo;
        #pragma unroll
        for (int r4 = 0; r4 < 4; ++r4) {
            int row = lane_hi * 4 + r4;
            out[(size_t)(row_base + row) * 128 + nc] = r0[r4];
            out[(size_t)(row_base + row + 16) * 128 + nc] = r1[r4];
            pwh[row * 128 + nc] = f2bf(w0[r4]);
            pwh[(row + 16) * 128 + nc] = f2bf(w1[r4]);
        }
    }

    // ===== Phase 6 (drain tail, no barrier): full gate sigmoid loop =====
    {
        unsigned short* pgh = pwh + 4096;
        float ag0[4], ag1[4];
        #pragma unroll
        for (int si = 0; si < 4; ++si) { ag0[si] = 0.f; ag1[si] = 0.f; }
        #pragma unroll 4
        for (int r = 0; r < 32; ++r) {
            float uv0 = *(const float*)(smem + M_U + (r * 128 + l) * 4);
            float uv1 = *(const float*)(smem + M_U + (r * 128 + l + 64) * 4);
            #pragma unroll
            for (int si = 0; si < 4; ++si) {
                ag0[si] += sigm(gbr0[si] + uv0);
                ag1[si] += sigm(gbr1[si] + uv1);
            }
        }
        #pragma unroll
        for (int si = 0; si < 4; ++si) {
            pgh[(sbase + si) * 128 + l]      = f2bf(ag0[si]);
            pgh[(sbase + si) * 128 + l + 64] = f2bf(ag1[si]);
        }
    }
}

// ---------------- finalize: 256 blocks x 512 threads; thread t owns copy t ----------------
__global__ __launch_bounds__(512) void fin_kernel(
    const float* __restrict__ memv, const unsigned char* __restrict__ ws,
    float* __restrict__ out2)
{
    __shared__ float red[8][32];
    __shared__ float fsum[32];
    int b = blockIdx.x, t = threadIdx.x;
    int wv = t >> 6, ln = t & 63;
    int col0 = b * 16;

    const unsigned short* cb = (const unsigned short*)(ws + ACC_OFF) + (size_t)t * 8192;
    ushort8_t a0 = *(const ushort8_t*)(cb + col0);
    ushort8_t a1 = *(const ushort8_t*)(cb + col0 + 8);
    ushort8_t gg0 = *(const ushort8_t*)(cb + 4096 + col0);
    ushort8_t gg1 = *(const ushort8_t*)(cb + 4096 + col0 + 8);

    float v[32];
    #pragma unroll
    for (int i = 0; i < 8; ++i) {
        v[i]      = bf2f(a0[i]);
        v[8 + i]  = bf2f(a1[i]);
        v[16 + i] = bf2f(gg0[i]);
        v[24 + i] = bf2f(gg1[i]);
    }
    #pragma unroll
    for (int m = 1; m < 64; m <<= 1) {
        #pragma unroll
        for (int i = 0; i < 32; ++i) v[i] += __shfl_xor(v[i], m);
    }
    if (ln == 0) {
        #pragma unroll
        for (int i = 0; i < 32; ++i) red[wv][i] = v[i];
    }
    __syncthreads();
    if (t < 32) {
        float s = 0.f;
        #pragma unroll
        for (int c = 0; c < 8; ++c) s += red[c][t];
        fsum[t] = s;
    }
    __syncthreads();
    if (t < 16) {
        float a = fsum[t] * (1.f / 16384.f);
        float g = fsum[16 + t] * (1.f / 16384.f);
        int i = col0 + t;
        out2[i] = memv[i] * (1.f - g) + a * g;
    }
}

// ---------------- launcher ----------------
extern "C" void kernel_launch(void* const* d_in, const int* in_sizes, int n_in,
                              void* d_out, int out_size, void* d_ws, size_t ws_size,
                              hipStream_t stream)
{
    (void)in_sizes; (void)n_in; (void)out_size; (void)ws_size;
    const float* x      = (const float*)d_in[0];
    const float* memv   = (const float*)d_in[1];
    const float* ln_g   = (const float*)d_in[2];
    const float* ln_b   = (const float*)d_in[3];
    const float* w_in   = (const float*)d_in[4];
    const float* b_in   = (const float*)d_in[5];
    const float* w_gate = (const float*)d_in[6];
    const float* b_gate = (const float*)d_in[7];
    float* out = (float*)d_out;
    unsigned char* ws = (unsigned char*)d_ws;

    hipLaunchKernelGGL(prep_kernel, dim3(273), dim3(256), 0, stream,
                       memv, w_in, b_in, w_gate, b_gate, ws);
    hipLaunchKernelGGL(main_kernel, dim3(NBLK), dim3(512), 0, stream,
                       x, ln_g, ln_b, b_in, ws, out);
    hipLaunchKernelGGL(fin_kernel, dim3(256), dim3(512), 0, stream,
                       memv, ws, out + 2097152);
}

// Round 14
// 47.878 us; speedup vs baseline: 1.6665x; 1.0844x over previous
//
#include <hip/hip_runtime.h>
#include <stdint.h>

typedef __attribute__((ext_vector_type(8))) short bfrag_t;    // 8 bf16
typedef __attribute__((ext_vector_type(4))) float floatx4;    // MFMA acc
typedef __attribute__((ext_vector_type(8))) unsigned short ushort8_t;

// ---------------- ws layout (bytes) ----------------
#define WFRAG_OFF   0            // bf16 [16kt][18nt][64lane][8j] = 294912
#define GB_OFF      294912       // f32 [32][128]
#define BU_OFF      311296       // f32 [128]
#define BS_OFF      311808       // f32 [32]
#define MEMFRAG_OFF 311936       // bf16 frag [8nt][64][8] = 8192
#define ACC_OFF     327680       // 512 x (accw[4096] | accg[4096]) bf16 = 8 MiB
#define NBLK        512

// ---------------- main LDS layout (bytes), NO overlay, 64 KiB ----------------
#define M_A     0        // bf16 swizzled A-tile [32r][512k] = 32768
#define M_XPF   32768    // bf16 B-frag [8nt][64][8] (k=rows) = 8192
#define M_U     40960    // f32 [32][128] = 16384
#define M_SC    57344    // f32 [32][32] = 4096
#define M_PR    61440    // bf16 A-frag [2mt][64][8] (probs, k=s) = 2048
#define M_PRT   63488    // bf16 A-frag [2mt][64][8] (probsT, k=r) = 2048
#define M_LDS   65536

__device__ __forceinline__ unsigned short f2bf(float f) {
    unsigned u = __float_as_uint(f);
    u += 0x7fffu + ((u >> 16) & 1u);
    return (unsigned short)(u >> 16);
}
__device__ __forceinline__ float bf2f(unsigned short h) {
    return __uint_as_float(((unsigned)h) << 16);
}
__device__ __forceinline__ float sigm(float v) {
    return __builtin_amdgcn_rcpf(1.0f + __expf(-v));
}
__device__ __forceinline__ void writefrag(unsigned short* wf, int k, int n, float v) {
    int kt = k >> 5, kk = k & 31;
    int lane = (n & 15) | ((kk >> 3) << 4);
    wf[(((kt * 18) + (n >> 4)) * 64 + lane) * 8 + (kk & 7)] = f2bf(v);
}

// ---------------- prep: frag weights, gate base, biases, mem frags ----------------
__global__ __launch_bounds__(256) void prep_kernel(
    const float* __restrict__ memv, const float* __restrict__ w_in,
    const float* __restrict__ b_in, const float* __restrict__ w_gate,
    const float* __restrict__ b_gate, unsigned char* __restrict__ ws)
{
    int bid = blockIdx.x, t = threadIdx.x;
    unsigned short* wfrag = (unsigned short*)(ws + WFRAG_OFF);
    const float* wg2 = w_gate + 128 * 128;

    if (bid < 256) {
        __shared__ float wrow[2][128];
        int k0 = bid * 2;
        wrow[t >> 7][t & 127] = w_in[(size_t)(k0 + (t >> 7)) * 128 + (t & 127)];
        __syncthreads();
        for (int kl = 0; kl < 2; ++kl) {
            int k = k0 + kl;
            float v;
            if (t < 128) {
                v = wrow[kl][t];
            } else {
                int d = t - 128;
                float acc = 0.f;
                #pragma unroll 16
                for (int j = 0; j < 128; ++j) acc += wrow[kl][j] * wg2[j * 128 + d];
                v = acc;
            }
            writefrag(wfrag, k, t, v);
            if (t < 32) {
                float acc = 0.f;
                #pragma unroll 16
                for (int d = 0; d < 128; ++d) acc += wrow[kl][d] * memv[t * 128 + d];
                writefrag(wfrag, k, 256 + t, acc);
            }
        }
    } else if (bid < 272) {
        int idx = (bid - 256) * 256 + t;
        int s = idx >> 7, d = idx & 127;
        float acc = b_gate[d];
        #pragma unroll 16
        for (int k = 0; k < 128; ++k) acc += memv[s * 128 + k] * w_gate[k * 128 + d];
        ((float*)(ws + GB_OFF))[idx] = acc;
    } else {
        if (t < 128) {
            float acc = 0.f;
            #pragma unroll 16
            for (int j = 0; j < 128; ++j) acc += b_in[j] * wg2[j * 128 + t];
            ((float*)(ws + BU_OFF))[t] = acc;
        }
        if (t < 32) {
            float acc = 0.f;
            #pragma unroll 16
            for (int d = 0; d < 128; ++d) acc += b_in[d] * memv[t * 128 + d];
            ((float*)(ws + BS_OFF))[t] = acc;
        }
        unsigned short* mfr = (unsigned short*)(ws + MEMFRAG_OFF);
        for (int idx = t; idx < 4096; idx += 256) {
            int s = idx >> 7, d = idx & 127;
            mfr[((d >> 4) * 64 + ((d & 15) | (((s >> 3) & 3) << 4))) * 8 + (s & 7)]
                = f2bf(memv[idx]);
        }
    }
}

// ---------------- main: 512 blocks x 512 threads, 32 rows/block ----------------
__global__ __launch_bounds__(512, 4) void main_kernel(
    const float* __restrict__ x,
    const float* __restrict__ ln_g, const float* __restrict__ ln_b,
    const float* __restrict__ b_in, unsigned char* __restrict__ ws,
    float* __restrict__ out)
{
    __shared__ char smem[M_LDS] __attribute__((aligned(16)));

    int tid = threadIdx.x;
    int w = tid >> 6, l = tid & 63;          // 8 waves
    int lane_lo = l & 15, lane_hi = l >> 4;
    int row_base = blockIdx.x * 32;

    int nf = (w < 2) ? 3 : 2;
    int nts[3] = {w, w + 8, 16 + w};
    const bfrag_t* wf = (const bfrag_t*)(ws + WFRAG_OFF);

    // ===== Phase 1: LayerNorm -> swizzled bf16 A tile [32][512] =====
    const float4* x4 = (const float4*)x;
    float4 g0 = ((const float4*)ln_g)[l];
    float4 g1 = ((const float4*)ln_g)[l + 64];
    float4 q0 = ((const float4*)ln_b)[l];
    float4 q1 = ((const float4*)ln_b)[l + 64];

    float4 xa[4], xb[4];
    #pragma unroll
    for (int i = 0; i < 4; ++i) {
        int r = w * 4 + i;
        xa[i] = x4[(size_t)(row_base + r) * 128 + l];
        xb[i] = x4[(size_t)(row_base + r) * 128 + 64 + l];
    }

    bfrag_t bcur[3], bnxt[3], bfar[3];
    #pragma unroll
    for (int i = 0; i < 3; ++i) {
        if (i < nf) {
            bcur[i] = wf[(0 * 18 + nts[i]) * 64 + l];
            bnxt[i] = wf[(1 * 18 + nts[i]) * 64 + l];
        }
    }
    float bin_v = b_in[w * 16 + lane_lo];
    float bu_v  = ((const float*)(ws + BU_OFF))[w * 16 + lane_lo];
    float bs_v  = (w < 2) ? ((const float*)(ws + BS_OFF))[w * 16 + lane_lo] : 0.f;

    #pragma unroll
    for (int i = 0; i < 4; ++i) {
        int r = w * 4 + i;
        float s1 = xa[i].x + xa[i].y + xa[i].z + xa[i].w + xb[i].x + xb[i].y + xb[i].z + xb[i].w;
        float s2 = xa[i].x*xa[i].x + xa[i].y*xa[i].y + xa[i].z*xa[i].z + xa[i].w*xa[i].w
                 + xb[i].x*xb[i].x + xb[i].y*xb[i].y + xb[i].z*xb[i].z + xb[i].w*xb[i].w;
        #pragma unroll
        for (int m = 1; m < 64; m <<= 1) {
            s1 += __shfl_xor(s1, m);
            s2 += __shfl_xor(s2, m);
        }
        float mu = s1 * (1.f / 512.f);
        float var = s2 * (1.f / 512.f) - mu * mu;
        float rs = rsqrtf(var + 1e-5f);
        float ya0 = (xa[i].x - mu) * rs * g0.x + q0.x;
        float ya1 = (xa[i].y - mu) * rs * g0.y + q0.y;
        float ya2 = (xa[i].z - mu) * rs * g0.z + q0.z;
        float ya3 = (xa[i].w - mu) * rs * g0.w + q0.w;
        float yb0 = (xb[i].x - mu) * rs * g1.x + q1.x;
        float yb1 = (xb[i].y - mu) * rs * g1.y + q1.y;
        float yb2 = (xb[i].z - mu) * rs * g1.z + q1.z;
        float yb3 = (xb[i].w - mu) * rs * g1.w + q1.w;
        unsigned long long pa =
            (unsigned long long)f2bf(ya0) | ((unsigned long long)f2bf(ya1) << 16) |
            ((unsigned long long)f2bf(ya2) << 32) | ((unsigned long long)f2bf(ya3) << 48);
        unsigned long long pb =
            (unsigned long long)f2bf(yb0) | ((unsigned long long)f2bf(yb1) << 16) |
            ((unsigned long long)f2bf(yb2) << 32) | ((unsigned long long)f2bf(yb3) << 48);
        int sw = (r & 7) << 4;
        *(unsigned long long*)(smem + M_A + ((r * 1024 + l * 8) ^ sw)) = pa;
        *(unsigned long long*)(smem + M_A + ((r * 1024 + 512 + l * 8) ^ sw)) = pb;
    }
    __syncthreads();                                     // barrier 1

    // ===== Phase 2: MFMA GEMM, 2-deep pipelined =====
    int swa = (l & 7) << 4;
    int ab0 = lane_lo * 1024 + (lane_hi << 4);
    int ab1 = (16 + lane_lo) * 1024 + (lane_hi << 4);

    floatx4 acc[3][2];
    #pragma unroll
    for (int i = 0; i < 3; ++i)
        #pragma unroll
        for (int mt = 0; mt < 2; ++mt)
            acc[i][mt] = (floatx4){0.f, 0.f, 0.f, 0.f};

    bfrag_t acur0, acur1, anxt0, anxt1, afar0, afar1;
    acur0 = *(const bfrag_t*)(smem + M_A + (ab0 ^ swa));
    acur1 = *(const bfrag_t*)(smem + M_A + (ab1 ^ swa));
    anxt0 = *(const bfrag_t*)(smem + M_A + ((ab0 + 64) ^ swa));
    anxt1 = *(const bfrag_t*)(smem + M_A + ((ab1 + 64) ^ swa));

    for (int kt = 0; kt < 16; ++kt) {
        if (kt < 14) {
            int ko = (kt + 2) * 64;
            afar0 = *(const bfrag_t*)(smem + M_A + ((ab0 + ko) ^ swa));
            afar1 = *(const bfrag_t*)(smem + M_A + ((ab1 + ko) ^ swa));
            #pragma unroll
            for (int i = 0; i < 3; ++i)
                if (i < nf) bfar[i] = wf[((kt + 2) * 18 + nts[i]) * 64 + l];
        }
        #pragma unroll
        for (int i = 0; i < 3; ++i) {
            if (i < nf) {
                acc[i][0] = __builtin_amdgcn_mfma_f32_16x16x32_bf16(acur0, bcur[i], acc[i][0], 0, 0, 0);
                acc[i][1] = __builtin_amdgcn_mfma_f32_16x16x32_bf16(acur1, bcur[i], acc[i][1], 0, 0, 0);
            }
        }
        acur0 = anxt0; acur1 = anxt1; anxt0 = afar0; anxt1 = afar1;
        #pragma unroll
        for (int i = 0; i < 3; ++i)
            if (i < nf) { bcur[i] = bnxt[i]; bnxt[i] = bfar[i]; }
    }

    // ===== Phase 3: epilogue =====
    {
        #pragma unroll
        for (int i = 0; i < 3; ++i) {
            if (i < nf) {
                int n = nts[i] * 16 + lane_lo;
                float bias = (i == 0) ? bin_v : ((i == 1) ? bu_v : bs_v);
                #pragma unroll
                for (int mt = 0; mt < 2; ++mt) {
                    #pragma unroll
                    for (int r4 = 0; r4 < 4; ++r4) {
                        int row = mt * 16 + lane_hi * 4 + r4;
                        float v = acc[i][mt][r4] + bias;
                        if (i == 0) {
                            int addr = M_XPF +
                                (((n >> 4) * 64 + ((n & 15) | ((row >> 3) << 4))) * 8
                                 + (row & 7)) * 2;
                            *(unsigned short*)(smem + addr) = f2bf(v);
                        } else if (i == 1) {
                            int d = n - 128;
                            *(float*)(smem + M_U + (row * 128 + d) * 4) = v;
                        } else {
                            int s = n - 256;
                            *(float*)(smem + M_SC + (row * 32 + s) * 4) = v;
                        }
                    }
                }
            }
        }
    }
    __syncthreads();                                     // barrier 2: SC/U/XPF ready

    // pre-issue phase-5/6 operands; latency hides under softmax
    bfrag_t bm = ((const bfrag_t*)(ws + MEMFRAG_OFF))[w * 64 + l];
    bfrag_t bx = *(const bfrag_t*)(smem + M_XPF + (w * 64 + l) * 16);
    int sbase = w * 4;
    const float* gb = (const float*)(ws + GB_OFF);
    float gbr0[4], gbr1[4];
    #pragma unroll
    for (int si = 0; si < 4; ++si) {
        gbr0[si] = gb[(sbase + si) * 128 + l];
        gbr1[si] = gb[(sbase + si) * 128 + l + 64];
    }

    // ===== Phase 4: softmax (4 rows/wave) =====
    #pragma unroll
    for (int i = 0; i < 4; ++i) {
        int r = w * 4 + i;
        int s = l & 31;
        float sc = *(const float*)(smem + M_SC + (r * 32 + s) * 4);
        float mx = sc;
        #pragma unroll
        for (int m = 1; m < 32; m <<= 1) mx = fmaxf(mx, __shfl_xor(mx, m));
        float e = __expf(sc - mx);
        float sum = e;
        #pragma unroll
        for (int m = 1; m < 32; m <<= 1) sum += __shfl_xor(sum, m);
        float p = e * __builtin_amdgcn_rcpf(sum);
        if (l < 32) {
            unsigned short pb = f2bf(p);
            *(unsigned short*)(smem + M_PR +
                (((r >> 4) * 64 + ((r & 15) + 16 * (s >> 3))) * 8 + (s & 7)) * 2) = pb;
            *(unsigned short*)(smem + M_PRT +
                (((s >> 4) * 64 + ((s & 15) + 16 * (r >> 3))) * 8 + (r & 7)) * 2) = pb;
        }
    }
    __syncthreads();                                     // barrier 3 (last barrier)

    // ===== Phase 5: read-GEMM (rc -> global) + write-GEMM (bf16 partial -> ws) =====
    unsigned short* pwh = (unsigned short*)(ws + ACC_OFF + (size_t)blockIdx.x * 16384);
    {
        bfrag_t pa0 = *(const bfrag_t*)(smem + M_PR + l * 16);
        bfrag_t pa1 = *(const bfrag_t*)(smem + M_PR + 1024 + l * 16);
        bfrag_t pat0 = *(const bfrag_t*)(smem + M_PRT + l * 16);
        bfrag_t pat1 = *(const bfrag_t*)(smem + M_PRT + 1024 + l * 16);

        floatx4 r0 = (floatx4){0.f, 0.f, 0.f, 0.f};
        floatx4 r1 = (floatx4){0.f, 0.f, 0.f, 0.f};
        r0 = __builtin_amdgcn_mfma_f32_16x16x32_bf16(pa0, bm, r0, 0, 0, 0);
        r1 = __builtin_amdgcn_mfma_f32_16x16x32_bf16(pa1, bm, r1, 0, 0, 0);
        floatx4 w0 = (floatx4){0.f, 0.f, 0.f, 0.f};
        floatx4 w1 = (floatx4){0.f, 0.f, 0.f, 0.f};
        w0 = __builtin_amdgcn_mfma_f32_16x16x32_bf16(pat0, bx, w0, 0, 0, 0);
        w1 = __builtin_amdgcn_mfma_f32_16x16x32_bf16(pat1, bx, w1, 0, 0, 0);

        int nc = w * 16 + lane_lo;
        #pragma unroll
        for (int r4 = 0; r4 < 4; ++r4) {
            int row = lane_hi * 4 + r4;
            out[(size_t)(row_base + row) * 128 + nc] = r0[r4];
            out[(size_t)(row_base + row + 16) * 128 + nc] = r1[r4];
            pwh[row * 128 + nc] = f2bf(w0[r4]);
            pwh[(row + 16) * 128 + nc] = f2bf(w1[r4]);
        }
    }

    // ===== Phase 6 (drain tail, no barrier): full gate sigmoid loop =====
    {
        unsigned short* pgh = pwh + 4096;
        float ag0[4], ag1[4];
        #pragma unroll
        for (int si = 0; si < 4; ++si) { ag0[si] = 0.f; ag1[si] = 0.f; }
        #pragma unroll 4
        for (int r = 0; r < 32; ++r) {
            float uv0 = *(const float*)(smem + M_U + (r * 128 + l) * 4);
            float uv1 = *(const float*)(smem + M_U + (r * 128 + l + 64) * 4);
            #pragma unroll
            for (int si = 0; si < 4; ++si) {
                ag0[si] += sigm(gbr0[si] + uv0);
                ag1[si] += sigm(gbr1[si] + uv1);
            }
        }
        #pragma unroll
        for (int si = 0; si < 4; ++si) {
            pgh[(sbase + si) * 128 + l]      = f2bf(ag0[si]);
            pgh[(sbase + si) * 128 + l + 64] = f2bf(ag1[si]);
        }
    }
}

// ---------------- finalize: 128 blocks x 512 threads, coalesced chunk reads ----------------
// Block b owns output elems [b*32, b*32+32). Per copy that is a full 64B line per array.
// chunk id = pass*512 + tid -> consecutive lanes read consecutive 16B chunks (coalesced).
__global__ __launch_bounds__(512) void fin_kernel(
    const float* __restrict__ memv, const unsigned char* __restrict__ ws,
    float* __restrict__ out2)
{
    __shared__ float red[8][8][8];   // [wave][sub][k]
    __shared__ float fsum[64];       // [arr*32 + elem_local]
    int b = blockIdx.x, t = threadIdx.x;
    int wv = t >> 6, l = t & 63;
    int sub = t & 7;                 // arr = sub>>2, q = sub&3
    int arr = sub >> 2, q = sub & 3;

    const unsigned char* base = ws + ACC_OFF;
    float v[8];
    #pragma unroll
    for (int i = 0; i < 8; ++i) v[i] = 0.f;

    #pragma unroll
    for (int j = 0; j < 8; ++j) {
        int copy = j * 64 + (t >> 3);
        ushort8_t u = *(const ushort8_t*)(base + (size_t)copy * 16384 + arr * 8192
                                          + b * 64 + q * 16);
        #pragma unroll
        for (int i = 0; i < 8; ++i) v[i] += bf2f(u[i]);
    }
    // reduce lanes sharing the same sub (lanes sub, sub+8, ..., sub+56)
    #pragma unroll
    for (int m = 8; m < 64; m <<= 1) {
        #pragma unroll
        for (int i = 0; i < 8; ++i) v[i] += __shfl_xor(v[i], m);
    }
    if (l < 8) {
        #pragma unroll
        for (int i = 0; i < 8; ++i) red[wv][l][i] = v[i];
    }
    __syncthreads();
    if (t < 64) {
        int sb = t >> 3, k = t & 7;   // sb: arr*4+q, k: elem within 16B chunk
        float s = 0.f;
        #pragma unroll
        for (int c = 0; c < 8; ++c) s += red[c][sb][k];
        fsum[(sb >> 2) * 32 + (sb & 3) * 8 + k] = s;
    }
    __syncthreads();
    if (t < 32) {
        float a = fsum[t] * (1.f / 16384.f);
        float g = fsum[32 + t] * (1.f / 16384.f);
        int e = b * 32 + t;
        out2[e] = memv[e] * (1.f - g) + a * g;
    }
}

// ---------------- launcher ----------------
extern "C" void kernel_launch(void* const* d_in, const int* in_sizes, int n_in,
                              void* d_out, int out_size, void* d_ws, size_t ws_size,
                              hipStream_t stream)
{
    (void)in_sizes; (void)n_in; (void)out_size; (void)ws_size;
    const float* x      = (const float*)d_in[0];
    const float* memv   = (const float*)d_in[1];
    const float* ln_g   = (const float*)d_in[2];
    const float* ln_b   = (const float*)d_in[3];
    const float* w_in   = (const float*)d_in[4];
    const float* b_in   = (const float*)d_in[5];
    const float* w_gate = (const float*)d_in[6];
    const float* b_gate = (const float*)d_in[7];
    float* out = (float*)d_out;
    unsigned char* ws = (unsigned char*)d_ws;

    hipLaunchKernelGGL(prep_kernel, dim3(273), dim3(256), 0, stream,
                       memv, w_in, b_in, w_gate, b_gate, ws);
    hipLaunchKernelGGL(main_kernel, dim3(NBLK), dim3(512), 0, stream,
                       x, ln_g, ln_b, b_in, ws, out);
    hipLaunchKernelGGL(fin_kernel, dim3(128), dim3(512), 0, stream,
                       memv, ws, out + 2097152);
}

// Round 16
// 42.521 us; speedup vs baseline: 1.8765x; 1.1260x over previous
//
#include <hip/hip_runtime.h>
#include <stdint.h>

typedef __attribute__((ext_vector_type(8))) short bfrag_t;    // 8 bf16
typedef __attribute__((ext_vector_type(4))) float floatx4;    // MFMA acc
typedef __attribute__((ext_vector_type(8))) unsigned short ushort8_t;

// ---------------- ws layout (bytes) ----------------
#define WFRAG_OFF   0            // bf16 [16kt][18nt][64lane][8j] = 294912
#define GB_OFF      294912       // f32 [32][128]
#define BU_OFF      311296       // f32 [128]
#define BS_OFF      311808       // f32 [32]
#define MEMFRAG_OFF 311936       // bf16 frag [8nt][64][8] = 8192
#define ACC_OFF     327680       // 512 x (accw[4096] | accg[4096]) bf16 = 8 MiB
#define NBLK        512

// ---------------- main LDS layout (bytes), NO overlay, 64 KiB ----------------
#define M_A     0        // bf16 swizzled A-tile [32r][512k] = 32768
#define M_XPF   32768    // bf16 B-frag [8nt][64][8] (k=rows) = 8192
#define M_U     40960    // f32 [32][128] = 16384
#define M_SC    57344    // f32 [32][32] = 4096
#define M_PR    61440    // bf16 A-frag [2mt][64][8] (probs, k=s) = 2048
#define M_PRT   63488    // bf16 A-frag [2mt][64][8] (probsT, k=r) = 2048
#define M_LDS   65536

__device__ __forceinline__ unsigned short f2bf(float f) {
    unsigned u = __float_as_uint(f);
    u += 0x7fffu + ((u >> 16) & 1u);
    return (unsigned short)(u >> 16);
}
__device__ __forceinline__ float bf2f(unsigned short h) {
    return __uint_as_float(((unsigned)h) << 16);
}
__device__ __forceinline__ void writefrag(unsigned short* wf, int k, int n, float v) {
    int kt = k >> 5, kk = k & 31;
    int lane = (n & 15) | ((kk >> 3) << 4);
    wf[(((kt * 18) + (n >> 4)) * 64 + lane) * 8 + (kk & 7)] = f2bf(v);
}

// ---------------- prep: frag weights, gate base, biases, mem frags ----------------
__global__ __launch_bounds__(256) void prep_kernel(
    const float* __restrict__ memv, const float* __restrict__ w_in,
    const float* __restrict__ b_in, const float* __restrict__ w_gate,
    const float* __restrict__ b_gate, unsigned char* __restrict__ ws)
{
    int bid = blockIdx.x, t = threadIdx.x;
    unsigned short* wfrag = (unsigned short*)(ws + WFRAG_OFF);
    const float* wg2 = w_gate + 128 * 128;

    if (bid < 256) {
        __shared__ float wrow[2][128];
        int k0 = bid * 2;
        wrow[t >> 7][t & 127] = w_in[(size_t)(k0 + (t >> 7)) * 128 + (t & 127)];
        __syncthreads();
        for (int kl = 0; kl < 2; ++kl) {
            int k = k0 + kl;
            float v;
            if (t < 128) {
                v = wrow[kl][t];
            } else {
                int d = t - 128;
                float acc = 0.f;
                #pragma unroll 16
                for (int j = 0; j < 128; ++j) acc += wrow[kl][j] * wg2[j * 128 + d];
                v = acc;
            }
            writefrag(wfrag, k, t, v);
            if (t < 32) {
                float acc = 0.f;
                #pragma unroll 16
                for (int d = 0; d < 128; ++d) acc += wrow[kl][d] * memv[t * 128 + d];
                writefrag(wfrag, k, 256 + t, acc);
            }
        }
    } else if (bid < 272) {
        int idx = (bid - 256) * 256 + t;
        int s = idx >> 7, d = idx & 127;
        float acc = b_gate[d];
        #pragma unroll 16
        for (int k = 0; k < 128; ++k) acc += memv[s * 128 + k] * w_gate[k * 128 + d];
        ((float*)(ws + GB_OFF))[idx] = acc;
    } else {
        if (t < 128) {
            float acc = 0.f;
            #pragma unroll 16
            for (int j = 0; j < 128; ++j) acc += b_in[j] * wg2[j * 128 + t];
            ((float*)(ws + BU_OFF))[t] = acc;
        }
        if (t < 32) {
            float acc = 0.f;
            #pragma unroll 16
            for (int d = 0; d < 128; ++d) acc += b_in[d] * memv[t * 128 + d];
            ((float*)(ws + BS_OFF))[t] = acc;
        }
        unsigned short* mfr = (unsigned short*)(ws + MEMFRAG_OFF);
        for (int idx = t; idx < 4096; idx += 256) {
            int s = idx >> 7, d = idx & 127;
            mfr[((d >> 4) * 64 + ((d & 15) | (((s >> 3) & 3) << 4))) * 8 + (s & 7)]
                = f2bf(memv[idx]);
        }
    }
}

// ---------------- main: 512 blocks x 512 threads, 32 rows/block ----------------
__global__ __launch_bounds__(512, 4) void main_kernel(
    const float* __restrict__ x,
    const float* __restrict__ ln_g, const float* __restrict__ ln_b,
    const float* __restrict__ b_in, unsigned char* __restrict__ ws,
    float* __restrict__ out)
{
    __shared__ char smem[M_LDS] __attribute__((aligned(16)));

    int tid = threadIdx.x;
    int w = tid >> 6, l = tid & 63;          // 8 waves
    int lane_lo = l & 15, lane_hi = l >> 4;
    int row_base = blockIdx.x * 32;

    int nf = (w < 2) ? 3 : 2;
    int nts[3] = {w, w + 8, 16 + w};
    const bfrag_t* wf = (const bfrag_t*)(ws + WFRAG_OFF);

    // ===== Phase 1: LayerNorm -> swizzled bf16 A tile [32][512] =====
    const float4* x4 = (const float4*)x;
    float4 g0 = ((const float4*)ln_g)[l];
    float4 g1 = ((const float4*)ln_g)[l + 64];
    float4 q0 = ((const float4*)ln_b)[l];
    float4 q1 = ((const float4*)ln_b)[l + 64];

    float4 xa[4], xb[4];
    #pragma unroll
    for (int i = 0; i < 4; ++i) {
        int r = w * 4 + i;
        xa[i] = x4[(size_t)(row_base + r) * 128 + l];
        xb[i] = x4[(size_t)(row_base + r) * 128 + 64 + l];
    }

    bfrag_t bcur[3], bnxt[3], bfar[3];
    #pragma unroll
    for (int i = 0; i < 3; ++i) {
        if (i < nf) {
            bcur[i] = wf[(0 * 18 + nts[i]) * 64 + l];
            bnxt[i] = wf[(1 * 18 + nts[i]) * 64 + l];
        }
    }
    float bin_v = b_in[w * 16 + lane_lo];
    float bu_v  = ((const float*)(ws + BU_OFF))[w * 16 + lane_lo];
    float bs_v  = (w < 2) ? ((const float*)(ws + BS_OFF))[w * 16 + lane_lo] : 0.f;

    #pragma unroll
    for (int i = 0; i < 4; ++i) {
        int r = w * 4 + i;
        float s1 = xa[i].x + xa[i].y + xa[i].z + xa[i].w + xb[i].x + xb[i].y + xb[i].z + xb[i].w;
        float s2 = xa[i].x*xa[i].x + xa[i].y*xa[i].y + xa[i].z*xa[i].z + xa[i].w*xa[i].w
                 + xb[i].x*xb[i].x + xb[i].y*xb[i].y + xb[i].z*xb[i].z + xb[i].w*xb[i].w;
        #pragma unroll
        for (int m = 1; m < 64; m <<= 1) {
            s1 += __shfl_xor(s1, m);
            s2 += __shfl_xor(s2, m);
        }
        float mu = s1 * (1.f / 512.f);
        float var = s2 * (1.f / 512.f) - mu * mu;
        float rs = rsqrtf(var + 1e-5f);
        float ya0 = (xa[i].x - mu) * rs * g0.x + q0.x;
        float ya1 = (xa[i].y - mu) * rs * g0.y + q0.y;
        float ya2 = (xa[i].z - mu) * rs * g0.z + q0.z;
        float ya3 = (xa[i].w - mu) * rs * g0.w + q0.w;
        float yb0 = (xb[i].x - mu) * rs * g1.x + q1.x;
        float yb1 = (xb[i].y - mu) * rs * g1.y + q1.y;
        float yb2 = (xb[i].z - mu) * rs * g1.z + q1.z;
        float yb3 = (xb[i].w - mu) * rs * g1.w + q1.w;
        unsigned long long pa =
            (unsigned long long)f2bf(ya0) | ((unsigned long long)f2bf(ya1) << 16) |
            ((unsigned long long)f2bf(ya2) << 32) | ((unsigned long long)f2bf(ya3) << 48);
        unsigned long long pb =
            (unsigned long long)f2bf(yb0) | ((unsigned long long)f2bf(yb1) << 16) |
            ((unsigned long long)f2bf(yb2) << 32) | ((unsigned long long)f2bf(yb3) << 48);
        int sw = (r & 7) << 4;
        *(unsigned long long*)(smem + M_A + ((r * 1024 + l * 8) ^ sw)) = pa;
        *(unsigned long long*)(smem + M_A + ((r * 1024 + 512 + l * 8) ^ sw)) = pb;
    }
    __syncthreads();                                     // barrier 1

    // ===== Phase 2: MFMA GEMM, 2-deep pipelined =====
    int swa = (l & 7) << 4;
    int ab0 = lane_lo * 1024 + (lane_hi << 4);
    int ab1 = (16 + lane_lo) * 1024 + (lane_hi << 4);

    floatx4 acc[3][2];
    #pragma unroll
    for (int i = 0; i < 3; ++i)
        #pragma unroll
        for (int mt = 0; mt < 2; ++mt)
            acc[i][mt] = (floatx4){0.f, 0.f, 0.f, 0.f};

    bfrag_t acur0, acur1, anxt0, anxt1, afar0, afar1;
    acur0 = *(const bfrag_t*)(smem + M_A + (ab0 ^ swa));
    acur1 = *(const bfrag_t*)(smem + M_A + (ab1 ^ swa));
    anxt0 = *(const bfrag_t*)(smem + M_A + ((ab0 + 64) ^ swa));
    anxt1 = *(const bfrag_t*)(smem + M_A + ((ab1 + 64) ^ swa));

    for (int kt = 0; kt < 16; ++kt) {
        if (kt < 14) {
            int ko = (kt + 2) * 64;
            afar0 = *(const bfrag_t*)(smem + M_A + ((ab0 + ko) ^ swa));
            afar1 = *(const bfrag_t*)(smem + M_A + ((ab1 + ko) ^ swa));
            #pragma unroll
            for (int i = 0; i < 3; ++i)
                if (i < nf) bfar[i] = wf[((kt + 2) * 18 + nts[i]) * 64 + l];
        }
        #pragma unroll
        for (int i = 0; i < 3; ++i) {
            if (i < nf) {
                acc[i][0] = __builtin_amdgcn_mfma_f32_16x16x32_bf16(acur0, bcur[i], acc[i][0], 0, 0, 0);
                acc[i][1] = __builtin_amdgcn_mfma_f32_16x16x32_bf16(acur1, bcur[i], acc[i][1], 0, 0, 0);
            }
        }
        acur0 = anxt0; acur1 = anxt1; anxt0 = afar0; anxt1 = afar1;
        #pragma unroll
        for (int i = 0; i < 3; ++i)
            if (i < nf) { bcur[i] = bnxt[i]; bnxt[i] = bfar[i]; }
    }

    // ===== Phase 3: epilogue =====
    {
        #pragma unroll
        for (int i = 0; i < 3; ++i) {
            if (i < nf) {
                int n = nts[i] * 16 + lane_lo;
                float bias = (i == 0) ? bin_v : ((i == 1) ? bu_v : bs_v);
                #pragma unroll
                for (int mt = 0; mt < 2; ++mt) {
                    #pragma unroll
                    for (int r4 = 0; r4 < 4; ++r4) {
                        int row = mt * 16 + lane_hi * 4 + r4;
                        float v = acc[i][mt][r4] + bias;
                        if (i == 0) {
                            int addr = M_XPF +
                                (((n >> 4) * 64 + ((n & 15) | ((row >> 3) << 4))) * 8
                                 + (row & 7)) * 2;
                            *(unsigned short*)(smem + addr) = f2bf(v);
                        } else if (i == 1) {
                            int d = n - 128;
                            *(float*)(smem + M_U + (row * 128 + d) * 4) = v;
                        } else {
                            int s = n - 256;
                            *(float*)(smem + M_SC + (row * 32 + s) * 4) = v;
                        }
                    }
                }
            }
        }
    }
    __syncthreads();                                     // barrier 2: SC/U/XPF ready

    // pre-issue phase-5/6 operands; latency hides under softmax
    bfrag_t bm = ((const bfrag_t*)(ws + MEMFRAG_OFF))[w * 64 + l];
    bfrag_t bx = *(const bfrag_t*)(smem + M_XPF + (w * 64 + l) * 16);
    int sbase = w * 4;
    const float* gb = (const float*)(ws + GB_OFF);
    float gbr0[4], gbr1[4];
    #pragma unroll
    for (int si = 0; si < 4; ++si) {
        gbr0[si] = gb[(sbase + si) * 128 + l];
        gbr1[si] = gb[(sbase + si) * 128 + l + 64];
    }

    // ===== Phase 4: softmax (4 rows/wave) =====
    #pragma unroll
    for (int i = 0; i < 4; ++i) {
        int r = w * 4 + i;
        int s = l & 31;
        float sc = *(const float*)(smem + M_SC + (r * 32 + s) * 4);
        float mx = sc;
        #pragma unroll
        for (int m = 1; m < 32; m <<= 1) mx = fmaxf(mx, __shfl_xor(mx, m));
        float e = __expf(sc - mx);
        float sum = e;
        #pragma unroll
        for (int m = 1; m < 32; m <<= 1) sum += __shfl_xor(sum, m);
        float p = e * __builtin_amdgcn_rcpf(sum);
        if (l < 32) {
            unsigned short pb = f2bf(p);
            *(unsigned short*)(smem + M_PR +
                (((r >> 4) * 64 + ((r & 15) + 16 * (s >> 3))) * 8 + (s & 7)) * 2) = pb;
            *(unsigned short*)(smem + M_PRT +
                (((s >> 4) * 64 + ((s & 15) + 16 * (r >> 3))) * 8 + (r & 7)) * 2) = pb;
        }
    }
    __syncthreads();                                     // barrier 3 (last barrier)

    // ===== Phase 5: read-GEMM (rc -> global) + write-GEMM (bf16 partial -> ws) =====
    unsigned short* pwh = (unsigned short*)(ws + ACC_OFF + (size_t)blockIdx.x * 16384);
    {
        bfrag_t pa0 = *(const bfrag_t*)(smem + M_PR + l * 16);
        bfrag_t pa1 = *(const bfrag_t*)(smem + M_PR + 1024 + l * 16);
        bfrag_t pat0 = *(const bfrag_t*)(smem + M_PRT + l * 16);
        bfrag_t pat1 = *(const bfrag_t*)(smem + M_PRT + 1024 + l * 16);

        floatx4 r0 = (floatx4){0.f, 0.f, 0.f, 0.f};
        floatx4 r1 = (floatx4){0.f, 0.f, 0.f, 0.f};
        r0 = __builtin_amdgcn_mfma_f32_16x16x32_bf16(pa0, bm, r0, 0, 0, 0);
        r1 = __builtin_amdgcn_mfma_f32_16x16x32_bf16(pa1, bm, r1, 0, 0, 0);
        floatx4 w0 = (floatx4){0.f, 0.f, 0.f, 0.f};
        floatx4 w1 = (floatx4){0.f, 0.f, 0.f, 0.f};
        w0 = __builtin_amdgcn_mfma_f32_16x16x32_bf16(pat0, bx, w0, 0, 0, 0);
        w1 = __builtin_amdgcn_mfma_f32_16x16x32_bf16(pat1, bx, w1, 0, 0, 0);

        int nc = w * 16 + lane_lo;
        #pragma unroll
        for (int r4 = 0; r4 < 4; ++r4) {
            int row = lane_hi * 4 + r4;
            out[(size_t)(row_base + row) * 128 + nc] = r0[r4];
            out[(size_t)(row_base + row + 16) * 128 + nc] = r1[r4];
            pwh[row * 128 + nc] = f2bf(w0[r4]);
            pwh[(row + 16) * 128 + nc] = f2bf(w1[r4]);
        }
    }

    // ===== Phase 6 (drain tail, no barrier): factored-sigmoid gate loop =====
    // sigma(g+u) = 1/(1 + e^-g * e^-u); hoist e^-g (8/thread), 2 exp per row-pair.
    {
        unsigned short* pgh = pwh + 4096;
        float En0[4], En1[4], ag0[4], ag1[4];
        #pragma unroll
        for (int si = 0; si < 4; ++si) {
            En0[si] = __expf(-gbr0[si]);
            En1[si] = __expf(-gbr1[si]);
            ag0[si] = 0.f; ag1[si] = 0.f;
        }
        #pragma unroll 4
        for (int r = 0; r < 32; ++r) {
            float uv0 = *(const float*)(smem + M_U + (r * 128 + l) * 4);
            float uv1 = *(const float*)(smem + M_U + (r * 128 + l + 64) * 4);
            float eu0 = __expf(-uv0);
            float eu1 = __expf(-uv1);
            #pragma unroll
            for (int si = 0; si < 4; ++si) {
                ag0[si] += __builtin_amdgcn_rcpf(1.f + En0[si] * eu0);
                ag1[si] += __builtin_amdgcn_rcpf(1.f + En1[si] * eu1);
            }
        }
        #pragma unroll
        for (int si = 0; si < 4; ++si) {
            pgh[(sbase + si) * 128 + l]      = f2bf(ag0[si]);
            pgh[(sbase + si) * 128 + l + 64] = f2bf(ag1[si]);
        }
    }
}

// ---------------- finalize: 128 blocks x 512 threads, coalesced chunk reads ----------------
__global__ __launch_bounds__(512) void fin_kernel(
    const float* __restrict__ memv, const unsigned char* __restrict__ ws,
    float* __restrict__ out2)
{
    __shared__ float red[8][8][8];   // [wave][sub][k]
    __shared__ float fsum[64];       // [arr*32 + elem_local]
    int b = blockIdx.x, t = threadIdx.x;
    int wv = t >> 6, l = t & 63;
    int sub = t & 7;
    int arr = sub >> 2, q = sub & 3;

    const unsigned char* base = ws + ACC_OFF;
    float v[8];
    #pragma unroll
    for (int i = 0; i < 8; ++i) v[i] = 0.f;

    #pragma unroll
    for (int j = 0; j < 8; ++j) {
        int copy = j * 64 + (t >> 3);
        ushort8_t u = *(const ushort8_t*)(base + (size_t)copy * 16384 + arr * 8192
                                          + b * 64 + q * 16);
        #pragma unroll
        for (int i = 0; i < 8; ++i) v[i] += bf2f(u[i]);
    }
    #pragma unroll
    for (int m = 8; m < 64; m <<= 1) {
        #pragma unroll
        for (int i = 0; i < 8; ++i) v[i] += __shfl_xor(v[i], m);
    }
    if (l < 8) {
        #pragma unroll
        for (int i = 0; i < 8; ++i) red[wv][l][i] = v[i];
    }
    __syncthreads();
    if (t < 64) {
        int sb = t >> 3, k = t & 7;
        float s = 0.f;
        #pragma unroll
        for (int c = 0; c < 8; ++c) s += red[c][sb][k];
        fsum[(sb >> 2) * 32 + (sb & 3) * 8 + k] = s;
    }
    __syncthreads();
    if (t < 32) {
        float a = fsum[t] * (1.f / 16384.f);
        float g = fsum[32 + t] * (1.f / 16384.f);
        int e = b * 32 + t;
        out2[e] = memv[e] * (1.f - g) + a * g;
    }
}

// ---------------- launcher ----------------
extern "C" void kernel_launch(void* const* d_in, const int* in_sizes, int n_in,
                              void* d_out, int out_size, void* d_ws, size_t ws_size,
                              hipStream_t stream)
{
    (void)in_sizes; (void)n_in; (void)out_size; (void)ws_size;
    const float* x      = (const float*)d_in[0];
    const float* memv   = (const float*)d_in[1];
    const float* ln_g   = (const float*)d_in[2];
    const float* ln_b   = (const float*)d_in[3];
    const float* w_in   = (const float*)d_in[4];
    const float* b_in   = (const float*)d_in[5];
    const float* w_gate = (const float*)d_in[6];
    const float* b_gate = (const float*)d_in[7];
    float* out = (float*)d_out;
    unsigned char* ws = (unsigned char*)d_ws;

    hipLaunchKernelGGL(prep_kernel, dim3(273), dim3(256), 0, stream,
                       memv, w_in, b_in, w_gate, b_gate, ws);
    hipLaunchKernelGGL(main_kernel, dim3(NBLK), dim3(512), 0, stream,
                       x, ln_g, ln_b, b_in, ws, out);
    hipLaunchKernelGGL(fin_kernel, dim3(128), dim3(512), 0, stream,
                       memv, ws, out + 2097152);
}

// Round 17
// 41.425 us; speedup vs baseline: 1.9261x; 1.0264x over previous
//
#include <hip/hip_runtime.h>
#include <hip/hip_bf16.h>
#include <stdint.h>

typedef __attribute__((ext_vector_type(8))) short bfrag_t;    // 8 bf16
typedef __attribute__((ext_vector_type(4))) float floatx4;    // MFMA acc
typedef __attribute__((ext_vector_type(8))) unsigned short ushort8_t;

// ---------------- ws layout (bytes) ----------------
#define WFRAG_OFF   0            // bf16 [16kt][18nt][64lane][8j] = 294912
#define GB_OFF      294912       // f32 [32][128]
#define BU_OFF      311296       // f32 [128]
#define BS_OFF      311808       // f32 [32]
#define MEMFRAG_OFF 311936       // bf16 frag [8nt][64][8] = 8192
#define ACC_OFF     327680       // 512 x (accw[4096] | accg[4096]) bf16 = 8 MiB
#define NBLK        512

// ---------------- main LDS layout (bytes), NO overlay, 64 KiB ----------------
#define M_A     0        // bf16 swizzled A-tile [32r][512k] = 32768
#define M_XPF   32768    // bf16 B-frag [8nt][64][8] (k=rows) = 8192
#define M_U     40960    // f32 [32][128] = 16384  (holds e^{-u}, not u)
#define M_SC    57344    // f32 [32][32] = 4096
#define M_PR    61440    // bf16 A-frag [2mt][64][8] (probs, k=s) = 2048
#define M_PRT   63488    // bf16 A-frag [2mt][64][8] (probsT, k=r) = 2048
#define M_LDS   65536

__device__ __forceinline__ unsigned short f2bf(float f) {
    union { __hip_bfloat16 b; unsigned short u; } cv;
    cv.b = __float2bfloat16(f);          // native RNE cvt (pairs fuse to v_cvt_pk_bf16_f32)
    return cv.u;
}
__device__ __forceinline__ float bf2f(unsigned short h) {
    return __uint_as_float(((unsigned)h) << 16);
}
__device__ __forceinline__ void writefrag(unsigned short* wf, int k, int n, float v) {
    int kt = k >> 5, kk = k & 31;
    int lane = (n & 15) | ((kk >> 3) << 4);
    wf[(((kt * 18) + (n >> 4)) * 64 + lane) * 8 + (kk & 7)] = f2bf(v);
}

// ---------------- prep: frag weights, gate base, biases, mem frags ----------------
__global__ __launch_bounds__(256) void prep_kernel(
    const float* __restrict__ memv, const float* __restrict__ w_in,
    const float* __restrict__ b_in, const float* __restrict__ w_gate,
    const float* __restrict__ b_gate, unsigned char* __restrict__ ws)
{
    int bid = blockIdx.x, t = threadIdx.x;
    unsigned short* wfrag = (unsigned short*)(ws + WFRAG_OFF);
    const float* wg2 = w_gate + 128 * 128;

    if (bid < 256) {
        __shared__ float wrow[2][128];
        int k0 = bid * 2;
        wrow[t >> 7][t & 127] = w_in[(size_t)(k0 + (t >> 7)) * 128 + (t & 127)];
        __syncthreads();
        for (int kl = 0; kl < 2; ++kl) {
            int k = k0 + kl;
            float v;
            if (t < 128) {
                v = wrow[kl][t];
            } else {
                int d = t - 128;
                float acc = 0.f;
                #pragma unroll 16
                for (int j = 0; j < 128; ++j) acc += wrow[kl][j] * wg2[j * 128 + d];
                v = acc;
            }
            writefrag(wfrag, k, t, v);
            if (t < 32) {
                float acc = 0.f;
                #pragma unroll 16
                for (int d = 0; d < 128; ++d) acc += wrow[kl][d] * memv[t * 128 + d];
                writefrag(wfrag, k, 256 + t, acc);
            }
        }
    } else if (bid < 272) {
        int idx = (bid - 256) * 256 + t;
        int s = idx >> 7, d = idx & 127;
        float acc = b_gate[d];
        #pragma unroll 16
        for (int k = 0; k < 128; ++k) acc += memv[s * 128 + k] * w_gate[k * 128 + d];
        ((float*)(ws + GB_OFF))[idx] = acc;
    } else {
        if (t < 128) {
            float acc = 0.f;
            #pragma unroll 16
            for (int j = 0; j < 128; ++j) acc += b_in[j] * wg2[j * 128 + t];
            ((float*)(ws + BU_OFF))[t] = acc;
        }
        if (t < 32) {
            float acc = 0.f;
            #pragma unroll 16
            for (int d = 0; d < 128; ++d) acc += b_in[d] * memv[t * 128 + d];
            ((float*)(ws + BS_OFF))[t] = acc;
        }
        unsigned short* mfr = (unsigned short*)(ws + MEMFRAG_OFF);
        for (int idx = t; idx < 4096; idx += 256) {
            int s = idx >> 7, d = idx & 127;
            mfr[((d >> 4) * 64 + ((d & 15) | (((s >> 3) & 3) << 4))) * 8 + (s & 7)]
                = f2bf(memv[idx]);
        }
    }
}

// ---------------- main: 512 blocks x 512 threads, 32 rows/block ----------------
__global__ __launch_bounds__(512, 4) void main_kernel(
    const float* __restrict__ x,
    const float* __restrict__ ln_g, const float* __restrict__ ln_b,
    const float* __restrict__ b_in, unsigned char* __restrict__ ws,
    float* __restrict__ out)
{
    __shared__ char smem[M_LDS] __attribute__((aligned(16)));

    int tid = threadIdx.x;
    int w = tid >> 6, l = tid & 63;          // 8 waves
    int lane_lo = l & 15, lane_hi = l >> 4;
    int row_base = blockIdx.x * 32;

    int nf = (w < 2) ? 3 : 2;
    int nts[3] = {w, w + 8, 16 + w};
    const bfrag_t* wf = (const bfrag_t*)(ws + WFRAG_OFF);

    // ===== Phase 1: LayerNorm -> swizzled bf16 A tile [32][512] =====
    const float4* x4 = (const float4*)x;
    float4 g0 = ((const float4*)ln_g)[l];
    float4 g1 = ((const float4*)ln_g)[l + 64];
    float4 q0 = ((const float4*)ln_b)[l];
    float4 q1 = ((const float4*)ln_b)[l + 64];

    float4 xa[4], xb[4];
    #pragma unroll
    for (int i = 0; i < 4; ++i) {
        int r = w * 4 + i;
        xa[i] = x4[(size_t)(row_base + r) * 128 + l];
        xb[i] = x4[(size_t)(row_base + r) * 128 + 64 + l];
    }

    bfrag_t bcur[3], bnxt[3], bfar[3];
    #pragma unroll
    for (int i = 0; i < 3; ++i) {
        if (i < nf) {
            bcur[i] = wf[(0 * 18 + nts[i]) * 64 + l];
            bnxt[i] = wf[(1 * 18 + nts[i]) * 64 + l];
        }
    }
    float bin_v = b_in[w * 16 + lane_lo];
    float bu_v  = ((const float*)(ws + BU_OFF))[w * 16 + lane_lo];
    float bs_v  = (w < 2) ? ((const float*)(ws + BS_OFF))[w * 16 + lane_lo] : 0.f;

    #pragma unroll
    for (int i = 0; i < 4; ++i) {
        int r = w * 4 + i;
        float s1 = xa[i].x + xa[i].y + xa[i].z + xa[i].w + xb[i].x + xb[i].y + xb[i].z + xb[i].w;
        float s2 = xa[i].x*xa[i].x + xa[i].y*xa[i].y + xa[i].z*xa[i].z + xa[i].w*xa[i].w
                 + xb[i].x*xb[i].x + xb[i].y*xb[i].y + xb[i].z*xb[i].z + xb[i].w*xb[i].w;
        #pragma unroll
        for (int m = 1; m < 64; m <<= 1) {
            s1 += __shfl_xor(s1, m);
            s2 += __shfl_xor(s2, m);
        }
        float mu = s1 * (1.f / 512.f);
        float var = s2 * (1.f / 512.f) - mu * mu;
        float rs = rsqrtf(var + 1e-5f);
        float ya0 = (xa[i].x - mu) * rs * g0.x + q0.x;
        float ya1 = (xa[i].y - mu) * rs * g0.y + q0.y;
        float ya2 = (xa[i].z - mu) * rs * g0.z + q0.z;
        float ya3 = (xa[i].w - mu) * rs * g0.w + q0.w;
        float yb0 = (xb[i].x - mu) * rs * g1.x + q1.x;
        float yb1 = (xb[i].y - mu) * rs * g1.y + q1.y;
        float yb2 = (xb[i].z - mu) * rs * g1.z + q1.z;
        float yb3 = (xb[i].w - mu) * rs * g1.w + q1.w;
        unsigned long long pa =
            (unsigned long long)f2bf(ya0) | ((unsigned long long)f2bf(ya1) << 16) |
            ((unsigned long long)f2bf(ya2) << 32) | ((unsigned long long)f2bf(ya3) << 48);
        unsigned long long pb =
            (unsigned long long)f2bf(yb0) | ((unsigned long long)f2bf(yb1) << 16) |
            ((unsigned long long)f2bf(yb2) << 32) | ((unsigned long long)f2bf(yb3) << 48);
        int sw = (r & 7) << 4;
        *(unsigned long long*)(smem + M_A + ((r * 1024 + l * 8) ^ sw)) = pa;
        *(unsigned long long*)(smem + M_A + ((r * 1024 + 512 + l * 8) ^ sw)) = pb;
    }
    __syncthreads();                                     // barrier 1

    // ===== Phase 2: MFMA GEMM, 2-deep pipelined =====
    int swa = (l & 7) << 4;
    int ab0 = lane_lo * 1024 + (lane_hi << 4);
    int ab1 = (16 + lane_lo) * 1024 + (lane_hi << 4);

    floatx4 acc[3][2];
    #pragma unroll
    for (int i = 0; i < 3; ++i)
        #pragma unroll
        for (int mt = 0; mt < 2; ++mt)
            acc[i][mt] = (floatx4){0.f, 0.f, 0.f, 0.f};

    bfrag_t acur0, acur1, anxt0, anxt1, afar0, afar1;
    acur0 = *(const bfrag_t*)(smem + M_A + (ab0 ^ swa));
    acur1 = *(const bfrag_t*)(smem + M_A + (ab1 ^ swa));
    anxt0 = *(const bfrag_t*)(smem + M_A + ((ab0 + 64) ^ swa));
    anxt1 = *(const bfrag_t*)(smem + M_A + ((ab1 + 64) ^ swa));

    for (int kt = 0; kt < 16; ++kt) {
        if (kt < 14) {
            int ko = (kt + 2) * 64;
            afar0 = *(const bfrag_t*)(smem + M_A + ((ab0 + ko) ^ swa));
            afar1 = *(const bfrag_t*)(smem + M_A + ((ab1 + ko) ^ swa));
            #pragma unroll
            for (int i = 0; i < 3; ++i)
                if (i < nf) bfar[i] = wf[((kt + 2) * 18 + nts[i]) * 64 + l];
        }
        #pragma unroll
        for (int i = 0; i < 3; ++i) {
            if (i < nf) {
                acc[i][0] = __builtin_amdgcn_mfma_f32_16x16x32_bf16(acur0, bcur[i], acc[i][0], 0, 0, 0);
                acc[i][1] = __builtin_amdgcn_mfma_f32_16x16x32_bf16(acur1, bcur[i], acc[i][1], 0, 0, 0);
            }
        }
        acur0 = anxt0; acur1 = anxt1; anxt0 = afar0; anxt1 = afar1;
        #pragma unroll
        for (int i = 0; i < 3; ++i)
            if (i < nf) { bcur[i] = bnxt[i]; bnxt[i] = bfar[i]; }
    }

    // ===== Phase 3: epilogue (stores e^{-u} for the gate phase) =====
    {
        #pragma unroll
        for (int i = 0; i < 3; ++i) {
            if (i < nf) {
                int n = nts[i] * 16 + lane_lo;
                float bias = (i == 0) ? bin_v : ((i == 1) ? bu_v : bs_v);
                #pragma unroll
                for (int mt = 0; mt < 2; ++mt) {
                    #pragma unroll
                    for (int r4 = 0; r4 < 4; ++r4) {
                        int row = mt * 16 + lane_hi * 4 + r4;
                        float v = acc[i][mt][r4] + bias;
                        if (i == 0) {
                            int addr = M_XPF +
                                (((n >> 4) * 64 + ((n & 15) | ((row >> 3) << 4))) * 8
                                 + (row & 7)) * 2;
                            *(unsigned short*)(smem + addr) = f2bf(v);
                        } else if (i == 1) {
                            int d = n - 128;
                            *(float*)(smem + M_U + (row * 128 + d) * 4) = __expf(-v);
                        } else {
                            int s = n - 256;
                            *(float*)(smem + M_SC + (row * 32 + s) * 4) = v;
                        }
                    }
                }
            }
        }
    }
    __syncthreads();                                     // barrier 2: SC/E_u/XPF ready

    // pre-issue phase-5/6 operands; latency hides under softmax
    bfrag_t bm = ((const bfrag_t*)(ws + MEMFRAG_OFF))[w * 64 + l];
    bfrag_t bx = *(const bfrag_t*)(smem + M_XPF + (w * 64 + l) * 16);
    int sbase = w * 4;
    const float* gb = (const float*)(ws + GB_OFF);
    float gbr0[4], gbr1[4];
    #pragma unroll
    for (int si = 0; si < 4; ++si) {
        gbr0[si] = gb[(sbase + si) * 128 + l];
        gbr1[si] = gb[(sbase + si) * 128 + l + 64];
    }

    // ===== Phase 4: softmax (4 rows/wave) =====
    #pragma unroll
    for (int i = 0; i < 4; ++i) {
        int r = w * 4 + i;
        int s = l & 31;
        float sc = *(const float*)(smem + M_SC + (r * 32 + s) * 4);
        float mx = sc;
        #pragma unroll
        for (int m = 1; m < 32; m <<= 1) mx = fmaxf(mx, __shfl_xor(mx, m));
        float e = __expf(sc - mx);
        float sum = e;
        #pragma unroll
        for (int m = 1; m < 32; m <<= 1) sum += __shfl_xor(sum, m);
        float p = e * __builtin_amdgcn_rcpf(sum);
        if (l < 32) {
            unsigned short pb = f2bf(p);
            *(unsigned short*)(smem + M_PR +
                (((r >> 4) * 64 + ((r & 15) + 16 * (s >> 3))) * 8 + (s & 7)) * 2) = pb;
            *(unsigned short*)(smem + M_PRT +
                (((s >> 4) * 64 + ((s & 15) + 16 * (r >> 3))) * 8 + (r & 7)) * 2) = pb;
        }
    }
    __syncthreads();                                     // barrier 3 (last barrier)

    // ===== Phase 5: read-GEMM (rc -> global) + write-GEMM (bf16 partial -> ws) =====
    unsigned short* pwh = (unsigned short*)(ws + ACC_OFF + (size_t)blockIdx.x * 16384);
    {
        bfrag_t pa0 = *(const bfrag_t*)(smem + M_PR + l * 16);
        bfrag_t pa1 = *(const bfrag_t*)(smem + M_PR + 1024 + l * 16);
        bfrag_t pat0 = *(const bfrag_t*)(smem + M_PRT + l * 16);
        bfrag_t pat1 = *(const bfrag_t*)(smem + M_PRT + 1024 + l * 16);

        floatx4 r0 = (floatx4){0.f, 0.f, 0.f, 0.f};
        floatx4 r1 = (floatx4){0.f, 0.f, 0.f, 0.f};
        r0 = __builtin_amdgcn_mfma_f32_16x16x32_bf16(pa0, bm, r0, 0, 0, 0);
        r1 = __builtin_amdgcn_mfma_f32_16x16x32_bf16(pa1, bm, r1, 0, 0, 0);
        floatx4 w0 = (floatx4){0.f, 0.f, 0.f, 0.f};
        floatx4 w1 = (floatx4){0.f, 0.f, 0.f, 0.f};
        w0 = __builtin_amdgcn_mfma_f32_16x16x32_bf16(pat0, bx, w0, 0, 0, 0);
        w1 = __builtin_amdgcn_mfma_f32_16x16x32_bf16(pat1, bx, w1, 0, 0, 0);

        int nc = w * 16 + lane_lo;
        #pragma unroll
        for (int r4 = 0; r4 < 4; ++r4) {
            int row = lane_hi * 4 + r4;
            out[(size_t)(row_base + row) * 128 + nc] = r0[r4];
            out[(size_t)(row_base + row + 16) * 128 + nc] = r1[r4];
            pwh[row * 128 + nc] = f2bf(w0[r4]);
            pwh[(row + 16) * 128 + nc] = f2bf(w1[r4]);
        }
    }

    // ===== Phase 6 (drain tail): gate loop, exp-free (E_u from LDS) =====
    // sigma(g+u) = 1/(1 + e^-g * e^-u); e^-g hoisted, e^-u precomputed in epilogue.
    {
        unsigned short* pgh = pwh + 4096;
        float En0[4], En1[4], ag0[4], ag1[4];
        #pragma unroll
        for (int si = 0; si < 4; ++si) {
            En0[si] = __expf(-gbr0[si]);
            En1[si] = __expf(-gbr1[si]);
            ag0[si] = 0.f; ag1[si] = 0.f;
        }
        #pragma unroll 4
        for (int r = 0; r < 32; ++r) {
            float eu0 = *(const float*)(smem + M_U + (r * 128 + l) * 4);
            float eu1 = *(const float*)(smem + M_U + (r * 128 + l + 64) * 4);
            #pragma unroll
            for (int si = 0; si < 4; ++si) {
                ag0[si] += __builtin_amdgcn_rcpf(1.f + En0[si] * eu0);
                ag1[si] += __builtin_amdgcn_rcpf(1.f + En1[si] * eu1);
            }
        }
        #pragma unroll
        for (int si = 0; si < 4; ++si) {
            pgh[(sbase + si) * 128 + l]      = f2bf(ag0[si]);
            pgh[(sbase + si) * 128 + l + 64] = f2bf(ag1[si]);
        }
    }
}

// ---------------- finalize: 128 blocks x 512 threads, coalesced chunk reads ----------------
__global__ __launch_bounds__(512) void fin_kernel(
    const float* __restrict__ memv, const unsigned char* __restrict__ ws,
    float* __restrict__ out2)
{
    __shared__ float red[8][8][8];   // [wave][sub][k]
    __shared__ float fsum[64];       // [arr*32 + elem_local]
    int b = blockIdx.x, t = threadIdx.x;
    int wv = t >> 6, l = t & 63;
    int sub = t & 7;
    int arr = sub >> 2, q = sub & 3;

    const unsigned char* base = ws + ACC_OFF;
    float v[8];
    #pragma unroll
    for (int i = 0; i < 8; ++i) v[i] = 0.f;

    #pragma unroll
    for (int j = 0; j < 8; ++j) {
        int copy = j * 64 + (t >> 3);
        ushort8_t u = *(const ushort8_t*)(base + (size_t)copy * 16384 + arr * 8192
                                          + b * 64 + q * 16);
        #pragma unroll
        for (int i = 0; i < 8; ++i) v[i] += bf2f(u[i]);
    }
    #pragma unroll
    for (int m = 8; m < 64; m <<= 1) {
        #pragma unroll
        for (int i = 0; i < 8; ++i) v[i] += __shfl_xor(v[i], m);
    }
    if (l < 8) {
        #pragma unroll
        for (int i = 0; i < 8; ++i) red[wv][l][i] = v[i];
    }
    __syncthreads();
    if (t < 64) {
        int sb = t >> 3, k = t & 7;
        float s = 0.f;
        #pragma unroll
        for (int c = 0; c < 8; ++c) s += red[c][sb][k];
        fsum[(sb >> 2) * 32 + (sb & 3) * 8 + k] = s;
    }
    __syncthreads();
    if (t < 32) {
        float a = fsum[t] * (1.f / 16384.f);
        float g = fsum[32 + t] * (1.f / 16384.f);
        int e = b * 32 + t;
        out2[e] = memv[e] * (1.f - g) + a * g;
    }
}

// ---------------- launcher ----------------
extern "C" void kernel_launch(void* const* d_in, const int* in_sizes, int n_in,
                              void* d_out, int out_size, void* d_ws, size_t ws_size,
                              hipStream_t stream)
{
    (void)in_sizes; (void)n_in; (void)out_size; (void)ws_size;
    const float* x      = (const float*)d_in[0];
    const float* memv   = (const float*)d_in[1];
    const float* ln_g   = (const float*)d_in[2];
    const float* ln_b   = (const float*)d_in[3];
    const float* w_in   = (const float*)d_in[4];
    const float* b_in   = (const float*)d_in[5];
    const float* w_gate = (const float*)d_in[6];
    const float* b_gate = (const float*)d_in[7];
    float* out = (float*)d_out;
    unsigned char* ws = (unsigned char*)d_ws;

    hipLaunchKernelGGL(prep_kernel, dim3(273), dim3(256), 0, stream,
                       memv, w_in, b_in, w_gate, b_gate, ws);
    hipLaunchKernelGGL(main_kernel, dim3(NBLK), dim3(512), 0, stream,
                       x, ln_g, ln_b, b_in, ws, out);
    hipLaunchKernelGGL(fin_kernel, dim3(128), dim3(512), 0, stream,
                       memv, ws, out + 2097152);
}